// Round 18
// baseline (548.654 us; speedup 1.0000x reference)
//
#include <hip/hip_runtime.h>
#include <math.h>

#define NN 100000
#define NE 1600000
#define NGB 391   // (NN+255)/256 = buckets of 256 nodes
#define NBKT 391
#define NB2 782   // blocks for 2-threads-per-node node kernels (128 nodes/block)

// ================= MFMA types =================
typedef __attribute__((ext_vector_type(8))) __bf16 bf16x8;
typedef __attribute__((ext_vector_type(4))) float f32x4;
union FR { unsigned u[4]; bf16x8 v; };

__device__ __forceinline__ f32x4 MFMA(bf16x8 a, bf16x8 b, f32x4 c) {
    return __builtin_amdgcn_mfma_f32_16x16x32_bf16(a, b, c, 0, 0, 0);
}
__device__ __forceinline__ unsigned pk2(float lo, float hi) {
    union { __bf16 b[2]; unsigned u; } P;
    P.b[0] = (__bf16)lo; P.b[1] = (__bf16)hi;
    return P.u;
}

// ---------------- repetition macros ----------------
#define R5(M,A)  M(0,A) M(1,A) M(2,A) M(3,A) M(4,A)
#define R7(M,A)  M(0,A) M(1,A) M(2,A) M(3,A) M(4,A) M(5,A) M(6,A)
#define R11(M,A) R7(M,A) M(7,A) M(8,A) M(9,A) M(10,A)
#define R16(M,A) M(0,A) M(1,A) M(2,A) M(3,A) M(4,A) M(5,A) M(6,A) M(7,A) \
                 M(8,A) M(9,A) M(10,A) M(11,A) M(12,A) M(13,A) M(14,A) M(15,A)
#define R16I(M,A) M(0,A) M(1,A) M(2,A) M(3,A) M(4,A) M(5,A) M(6,A) M(7,A) \
                  M(8,A) M(9,A) M(10,A) M(11,A) M(12,A) M(13,A) M(14,A) M(15,A)
#define R64(M,A) \
  M(0,A) M(1,A) M(2,A) M(3,A) M(4,A) M(5,A) M(6,A) M(7,A) \
  M(8,A) M(9,A) M(10,A) M(11,A) M(12,A) M(13,A) M(14,A) M(15,A) \
  M(16,A) M(17,A) M(18,A) M(19,A) M(20,A) M(21,A) M(22,A) M(23,A) \
  M(24,A) M(25,A) M(26,A) M(27,A) M(28,A) M(29,A) M(30,A) M(31,A) \
  M(32,A) M(33,A) M(34,A) M(35,A) M(36,A) M(37,A) M(38,A) M(39,A) \
  M(40,A) M(41,A) M(42,A) M(43,A) M(44,A) M(45,A) M(46,A) M(47,A) \
  M(48,A) M(49,A) M(50,A) M(51,A) M(52,A) M(53,A) M(54,A) M(55,A) \
  M(56,A) M(57,A) M(58,A) M(59,A) M(60,A) M(61,A) M(62,A) M(63,A)

#define DECL_H1(J,P) float h1_##J = (P)[J];
#define FMA_L1(J,K)  h1_##J = fmaf(ein_##K, wrow[J], h1_##J);
#define ROW_L1(K,W)  { const float* wrow = (W) + (K)*64; R64(FMA_L1,K) }
#define RELU_H1(J,A) h1_##J = fmaxf(h1_##J, 0.0f);
#define DECL_A(K,P)  float a_##K = (P)[K];
#define FMA_L2(Q,K)  a_##K = fmaf(h1_##Q, w2p[(K)*64+Q], a_##K);
#define ROW_L2(K,A)  R64(FMA_L2,K)
#define FOLD_E(K,A) { float r = fmaxf(a_##K, 0.0f); \
  o_0 = fmaf(r, w3p[(K)*5+0], o_0); o_1 = fmaf(r, w3p[(K)*5+1], o_1); \
  o_2 = fmaf(r, w3p[(K)*5+2], o_2); o_3 = fmaf(r, w3p[(K)*5+3], o_3); \
  o_4 = fmaf(r, w3p[(K)*5+4], o_4); }
#define FOLD_N(K,A)  dphi = fmaf(fmaxf(a_##K, 0.0f), w3p[K], dphi);
#define DECL_H2(K,G) float h2##G##_##K;
#define ASG_H2(K,G)  h2##G##_##K = fmaxf(a_##K, 0.0f);
#define L2BLK(G,B)   { const float* w2p = dw2t + (B)*1024; const float* b2p = db2 + (B)*16; \
                       R16(DECL_A,b2p) R16(ROW_L2,0) R16(ASG_H2,G) }
#define FMA_L3A(Q,K) a_##K = fmaf(h2A_##Q, w3p[(K)*64+Q],    a_##K);
#define FMA_L3B(Q,K) a_##K = fmaf(h2B_##Q, w3p[(K)*64+16+Q], a_##K);
#define FMA_L3C(Q,K) a_##K = fmaf(h2C_##Q, w3p[(K)*64+32+Q], a_##K);
#define FMA_L3D(Q,K) a_##K = fmaf(h2D_##Q, w3p[(K)*64+48+Q], a_##K);
#define ROW_L3(K,A)  R16I(FMA_L3A,K) R16I(FMA_L3B,K) R16I(FMA_L3C,K) R16I(FMA_L3D,K)
#define FOLD_D(K,A)  o = fmaf(fmaxf(a_##K, 0.0f), w4p[K], o);

// split-decoder helpers (wave-pair version)
#define DECL_LO(K,A) float lo_##K;
#define DECL_HI(K,A) float hi_##K;
#define ASG_LO(K,A)  lo_##K = fmaxf(a_##K, 0.0f);
#define ASG_HI(K,A)  hi_##K = fmaxf(a_##K, 0.0f);
#define ST_LO(K,P)   (P)[K]      = lo_##K;
#define ST_HI(K,P)   (P)[16+K]   = hi_##K;
#define LD_H2A(K,P)  h2A_##K = (P)[K];
#define LD_H2B(K,P)  h2B_##K = (P)[16+K];
#define LD_H2C(K,P)  h2C_##K = (P)[32+K];
#define LD_H2D(K,P)  h2D_##K = (P)[48+K];

#define EDGE_MLP_BODY \
    R64(DECL_H1, eb1) \
    R11(ROW_L1, ew1) \
    R64(RELU_H1, 0) \
    float o_0=eb3[0], o_1=eb3[1], o_2=eb3[2], o_3=eb3[3], o_4=eb3[4]; \
    for (int kb = 0; kb < 4; kb++) { \
        const float* w2p = ew2t + kb * 1024; \
        const float* b2p = eb2 + kb * 16; \
        const float* w3p = ew3 + kb * 80; \
        R16(DECL_A, b2p) \
        R16(ROW_L2, 0) \
        R16(FOLD_E, 0) \
    }

#define NODE_MLP_BODY \
    R64(DECL_H1, nb1) \
    R7(ROW_L1, nw1) \
    R64(RELU_H1, 0) \
    float dphi = nb3[0]; \
    for (int kb = 0; kb < 4; kb++) { \
        const float* w2p = nw2t + kb * 1024; \
        const float* b2p = nb2 + kb * 16; \
        const float* w3p = nw3 + kb * 16; \
        R16(DECL_A, b2p) \
        R16(ROW_L2, 0) \
        R16(FOLD_N, 0) \
    }

#define DECODER_BODY \
    R64(DECL_H1, db1) \
    R5(ROW_L1, dw1) \
    R64(RELU_H1, 0) \
    R16(DECL_H2, A) R16(DECL_H2, B) R16(DECL_H2, C) R16(DECL_H2, D) \
    L2BLK(A, 0) L2BLK(B, 1) L2BLK(C, 2) L2BLK(D, 3) \
    float o = db4[0]; \
    for (int jb = 0; jb < 4; jb++) { \
        const float* w3p = dw3t + jb*1024; \
        const float* b3p = db3 + jb*16; \
        const float* w4p = dw4 + jb*16; \
        R16(DECL_A, b3p) \
        R16(ROW_L3, 0) \
        R16(FOLD_D, 0) \
    }

// ---------------- small utility kernels ----------------
__global__ void transpose64(const float* __restrict__ in, float* __restrict__ out) {
    int j = blockIdx.x, k = threadIdx.x;
    out[j * 64 + k] = in[k * 64 + j];
}

__global__ void prep_wb(const float* __restrict__ ew1, const float* __restrict__ eb1,
                        const float* __restrict__ ew2,
                        const float* __restrict__ ew3, const float* __restrict__ eb2,
                        unsigned short* __restrict__ w1t, unsigned short* __restrict__ w2t,
                        float* __restrict__ w3p) {
    int t = threadIdx.x;
    for (int idx = t; idx < 64*32; idx += 256) {
        int m = idx >> 5, k = idx & 31;
        float v = (k < 11) ? ew1[k*64 + m] : (k == 11 ? eb1[m] : 0.0f);
        union { __bf16 b; unsigned short u; } U; U.b = (__bf16)v;
        w1t[idx] = U.u;
    }
    for (int idx = t; idx < 64*64; idx += 256) {
        int m = idx >> 6, k = idx & 63;
        union { __bf16 b; unsigned short u; } U; U.b = (__bf16)(ew2[k*64 + m]);
        w2t[idx] = U.u;
    }
    for (int idx = t; idx < 64*8; idx += 256) {
        int F = idx >> 3, j = idx & 7;
        w3p[idx] = (j < 5) ? ew3[F*5 + j] : (j == 5 ? eb2[F] : 0.0f);
    }
}

__global__ void init_xw(const float* __restrict__ x, float* __restrict__ xw,
                        int* __restrict__ bsum, int* __restrict__ bcur) {
    int i = blockIdx.x * blockDim.x + threadIdx.x;
    if (i < NN) {
#pragma unroll
        for (int j = 0; j < 5; j++) xw[i*5+j] = x[i*5+j];
    }
    if (i < 512) bsum[i] = 0;
    if (i < NBKT) bcur[i] = 0;
}

__global__ __launch_bounds__(256)
void bhist_kernel(const int* __restrict__ dst, int* __restrict__ bsum) {
    __shared__ int h[NBKT];
    int t = threadIdx.x;
    for (int i = t; i < NBKT; i += 256) h[i] = 0;
    __syncthreads();
    int eb = blockIdx.x * 6400;
#pragma unroll
    for (int it = 0; it < 25; ++it) {
        int e = eb + it*256 + t;
        atomicAdd(&h[dst[e] >> 8], 1);
    }
    __syncthreads();
    for (int i = t; i < NBKT; i += 256)
        if (h[i]) atomicAdd(&bsum[i], h[i]);
}

__global__ void scanb_kernel(const int* __restrict__ bsum, int* __restrict__ boff) {
    __shared__ int s[512];
    int t = threadIdx.x;
    int v0 = (t < NGB) ? bsum[t] : 0;
    s[t] = v0;
    __syncthreads();
    for (int o = 1; o < 512; o <<= 1) {
        int v = (t >= o) ? s[t - o] : 0;
        __syncthreads();
        s[t] += v;
        __syncthreads();
    }
    if (t < NGB) boff[t] = s[t] - v0;   // exclusive
}

__global__ __launch_bounds__(256)
void sort_pass1(const int* __restrict__ dst, const int* __restrict__ boff,
                int* __restrict__ bcur, int* __restrict__ ebkt) {
    __shared__ int hist[NBKT];
    __shared__ int s[512];
    __shared__ int scanBase[NBKT];
    __shared__ int cur[NBKT];
    __shared__ int gbase[NBKT];
    __shared__ int stage[6400];
    int t = threadIdx.x;
    int eb = blockIdx.x * 6400;

    for (int i = t; i < NBKT; i += 256) hist[i] = 0;
    __syncthreads();
#pragma unroll
    for (int it = 0; it < 25; ++it) {
        int e = eb + it*256 + t;
        atomicAdd(&hist[dst[e] >> 8], 1);
    }
    __syncthreads();
    s[t]       = (t < NBKT) ? hist[t] : 0;
    s[t + 256] = (t + 256 < NBKT) ? hist[t + 256] : 0;
    __syncthreads();
    for (int o = 1; o < 512; o <<= 1) {
        int v0 = (t >= o) ? s[t - o] : 0;
        int v1 = ((t + 256) >= o) ? s[t + 256 - o] : 0;
        __syncthreads();
        s[t] += v0; s[t + 256] += v1;
        __syncthreads();
    }
    for (int i = t; i < NBKT; i += 256) {
        int ex = s[i] - hist[i];
        scanBase[i] = ex;
        cur[i] = ex;
        gbase[i] = (hist[i] > 0) ? atomicAdd(&bcur[i], hist[i]) : 0;
    }
    __syncthreads();
#pragma unroll
    for (int it = 0; it < 25; ++it) {
        int e = eb + it*256 + t;
        int b = dst[e] >> 8;
        int ls = atomicAdd(&cur[b], 1);
        stage[ls] = (b << 21) | e;
    }
    __syncthreads();
#pragma unroll
    for (int it = 0; it < 25; ++it) {
        int k = it*256 + t;
        int p = stage[k];
        int b = p >> 21;
        int e = p & 0x1FFFFF;
        ebkt[boff[b] + gbase[b] + (k - scanBase[b])] = e;
    }
}

__global__ __launch_bounds__(256)
void sort_pass2(const int* __restrict__ ebkt, const int* __restrict__ dst,
                const int* __restrict__ boff, const int* __restrict__ bsum,
                int* __restrict__ eidx, int* __restrict__ cnt, int* __restrict__ start) {
    __shared__ int ncnt[256];
    __shared__ int s[256];
    __shared__ int lbase[256];
    __shared__ int lcur[256];
    __shared__ int outst[6144];
    int b = blockIdx.x, t = threadIdx.x;
    int node0 = b << 8;
    int nb = bsum[b];
    int base = boff[b];

    ncnt[t] = 0;
    __syncthreads();
    for (int k = t; k < nb; k += 256) {
        int e = ebkt[base + k];
        atomicAdd(&ncnt[dst[e] - node0], 1);
    }
    __syncthreads();
    int c = ncnt[t];
    s[t] = c;
    __syncthreads();
    for (int o = 1; o < 256; o <<= 1) {
        int v = (t >= o) ? s[t - o] : 0;
        __syncthreads();
        s[t] += v;
        __syncthreads();
    }
    lbase[t] = s[t] - c;
    lcur[t] = 0;
    __syncthreads();
    for (int k = t; k < nb; k += 256) {
        int e = ebkt[base + k];
        int dl = dst[e] - node0;
        int ls = lbase[dl] + atomicAdd(&lcur[dl], 1);
        outst[ls] = e;
    }
    __syncthreads();
    for (int k = t; k < nb; k += 256) eidx[base + k] = outst[k];
    int i = node0 + t;
    if (i < NN) { cnt[i] = c; start[i] = base + lbase[t]; }
}

// ---------------- MFMA edge kernel ----------------
#define EPI1(MT,RR,C2) { \
    int F = (MT)*16 + 4*g + (RR); \
    const float4* wq = reinterpret_cast<const float4*>(w3p + F*8); \
    float4 wA = wq[0]; float4 wB = wq[1]; \
    float hh = fmaxf(C2[RR] + wB.y, 0.f); \
    o0=fmaf(hh,wA.x,o0); o1=fmaf(hh,wA.y,o1); o2=fmaf(hh,wA.z,o2); \
    o3=fmaf(hh,wA.w,o3); o4=fmaf(hh,wB.x,o4); }

template<int NT>
__device__ __forceinline__ void proc_nt(
    unsigned q0, unsigned q1, unsigned q2, unsigned q3, unsigned q4, unsigned q5,
    FR a1_0, FR a1_1, FR a1_2, FR a1_3,
    FR a2_00, FR a2_01, FR a2_10, FR a2_11,
    FR a2_20, FR a2_21, FR a2_30, FR a2_31,
    const float* __restrict__ w3p,
    int g, int c, int srcA, int srcB, bool hi2,
    float& s0, float& s1, float& s2, float& s3, float& s4)
{
    f32x4 z = {0.f, 0.f, 0.f, 0.f};

    int srcl = NT*16 + c;
    unsigned m0=__shfl(q0,srcl), m1=__shfl(q1,srcl), m2=__shfl(q2,srcl);
    unsigned m3=__shfl(q3,srcl), m4=__shfl(q4,srcl), m5=__shfl(q5,srcl);
    FR B;
    B.u[0] = (g==0)?m0:((g==1)?m4:0u);
    B.u[1] = (g==0)?m1:((g==1)?m5:0u);
    B.u[2] = (g==0)?m2:0u;
    B.u[3] = (g==0)?m3:0u;
    f32x4 c1_0 = MFMA(a1_0.v, B.v, z);
    f32x4 c1_1 = MFMA(a1_1.v, B.v, z);
    f32x4 c1_2 = MFMA(a1_2.v, B.v, z);
    f32x4 c1_3 = MFMA(a1_3.v, B.v, z);

    unsigned pk01_0 = pk2(fmaxf(c1_0[0],0.f), fmaxf(c1_0[1],0.f));
    unsigned pk23_0 = pk2(fmaxf(c1_0[2],0.f), fmaxf(c1_0[3],0.f));
    unsigned pk01_1 = pk2(fmaxf(c1_1[0],0.f), fmaxf(c1_1[1],0.f));
    unsigned pk23_1 = pk2(fmaxf(c1_1[2],0.f), fmaxf(c1_1[3],0.f));
    unsigned pk01_2 = pk2(fmaxf(c1_2[0],0.f), fmaxf(c1_2[1],0.f));
    unsigned pk23_2 = pk2(fmaxf(c1_2[2],0.f), fmaxf(c1_2[3],0.f));
    unsigned pk01_3 = pk2(fmaxf(c1_3[0],0.f), fmaxf(c1_3[1],0.f));
    unsigned pk23_3 = pk2(fmaxf(c1_3[2],0.f), fmaxf(c1_3[3],0.f));

    FR B20;
    {
        unsigned sA0=__shfl(pk01_0,srcA), sA1=__shfl(pk01_1,srcA);
        unsigned sB0=__shfl(pk23_0,srcA), sB1=__shfl(pk23_1,srcA);
        unsigned sC0=__shfl(pk01_0,srcB), sC1=__shfl(pk01_1,srcB);
        unsigned sD0=__shfl(pk23_0,srcB), sD1=__shfl(pk23_1,srcB);
        B20.u[0]=hi2?sA1:sA0; B20.u[1]=hi2?sB1:sB0;
        B20.u[2]=hi2?sC1:sC0; B20.u[3]=hi2?sD1:sD0;
    }
    FR B21;
    {
        unsigned sA0=__shfl(pk01_2,srcA), sA1=__shfl(pk01_3,srcA);
        unsigned sB0=__shfl(pk23_2,srcA), sB1=__shfl(pk23_3,srcA);
        unsigned sC0=__shfl(pk01_2,srcB), sC1=__shfl(pk01_3,srcB);
        unsigned sD0=__shfl(pk23_2,srcB), sD1=__shfl(pk23_3,srcB);
        B21.u[0]=hi2?sA1:sA0; B21.u[1]=hi2?sB1:sB0;
        B21.u[2]=hi2?sC1:sC0; B21.u[3]=hi2?sD1:sD0;
    }
    f32x4 c2_0 = MFMA(a2_00.v, B20.v, z);   c2_0 = MFMA(a2_01.v, B21.v, c2_0);
    f32x4 c2_1 = MFMA(a2_10.v, B20.v, z);   c2_1 = MFMA(a2_11.v, B21.v, c2_1);
    f32x4 c2_2 = MFMA(a2_20.v, B20.v, z);   c2_2 = MFMA(a2_21.v, B21.v, c2_2);
    f32x4 c2_3 = MFMA(a2_30.v, B20.v, z);   c2_3 = MFMA(a2_31.v, B21.v, c2_3);

    float o0=0.f, o1=0.f, o2=0.f, o3=0.f, o4=0.f;
    EPI1(0,0,c2_0) EPI1(0,1,c2_0) EPI1(0,2,c2_0) EPI1(0,3,c2_0)
    EPI1(1,0,c2_1) EPI1(1,1,c2_1) EPI1(1,2,c2_1) EPI1(1,3,c2_1)
    EPI1(2,0,c2_2) EPI1(2,1,c2_2) EPI1(2,2,c2_2) EPI1(2,3,c2_2)
    EPI1(3,0,c2_3) EPI1(3,1,c2_3) EPI1(3,2,c2_3) EPI1(3,3,c2_3)

    o0 += __shfl_xor(o0,16); o0 += __shfl_xor(o0,32);
    o1 += __shfl_xor(o1,16); o1 += __shfl_xor(o1,32);
    o2 += __shfl_xor(o2,16); o2 += __shfl_xor(o2,32);
    o3 += __shfl_xor(o3,16); o3 += __shfl_xor(o3,32);
    o4 += __shfl_xor(o4,16); o4 += __shfl_xor(o4,32);

    if (g == NT) { s0 = o0; s1 = o1; s2 = o2; s3 = o3; s4 = o4; }
}

#define LOAD_A1(MT) FR a1_##MT; \
    *reinterpret_cast<uint4*>(a1_##MT.u) = \
        *reinterpret_cast<const uint4*>(w1t + ((MT)*16 + c)*32 + 8*g);
#define LOAD_A2(MT) FR a2_##MT##_0, a2_##MT##_1; \
    *reinterpret_cast<uint4*>(a2_##MT##_0.u) = \
        *reinterpret_cast<const uint4*>(w2t + ((MT)*16 + c)*64 + 8*g); \
    *reinterpret_cast<uint4*>(a2_##MT##_1.u) = \
        *reinterpret_cast<const uint4*>(w2t + ((MT)*16 + c)*64 + 32 + 8*g);

__global__ __launch_bounds__(256, 4)
void edge_mfma(const float* __restrict__ xw, const float* __restrict__ edge_attr,
               const int* __restrict__ src_idx, const int* __restrict__ dst_idx,
               const unsigned short* __restrict__ w1t, const unsigned short* __restrict__ w2t,
               const float* __restrict__ w3p, const float* __restrict__ eb3,
               float* __restrict__ eout) {
    int tid = threadIdx.x;
    int l = tid & 63;
    int g = l >> 4;
    int c = l & 15;
    int e = blockIdx.x * 256 + tid;

    int s = src_idx[e];
    int d = dst_idx[e];
    float xs_0=xw[s*5+0], xs_1=xw[s*5+1], xs_2=xw[s*5+2], xs_4=xw[s*5+4];
    float xd_0=xw[d*5+0], xd_1=xw[d*5+1], xd_2=xw[d*5+2], xd_4=xw[d*5+4];
    float ea_0=edge_attr[(size_t)e*5+0], ea_1=edge_attr[(size_t)e*5+1],
          ea_2=edge_attr[(size_t)e*5+2], ea_3=edge_attr[(size_t)e*5+3],
          ea_4=edge_attr[(size_t)e*5+4];

    float ein_0 = xd_0 - xs_0;
    float ein_1 = xd_1 - xs_1;
    float ein_2 = xd_2 - xs_2;
    float ein_3 = sqrtf(ein_0*ein_0 + ein_1*ein_1 + ein_2*ein_2);

    unsigned q0 = pk2(ein_0, ein_1);
    unsigned q1 = pk2(ein_2, ein_3);
    unsigned q2 = pk2(ea_0, ea_1);
    unsigned q3 = pk2(ea_2, ea_3);
    unsigned q4 = pk2(ea_4, xs_4);
    unsigned q5 = pk2(xd_4, 1.0f);

    LOAD_A1(0) LOAD_A1(1) LOAD_A1(2) LOAD_A1(3)
    LOAD_A2(0) LOAD_A2(1) LOAD_A2(2) LOAD_A2(3)

    int srcA = (g & 1) * 32 + c;
    int srcB = srcA + 16;
    bool hi2 = (g & 2) != 0;

    float s0 = 0.f, s1 = 0.f, s2 = 0.f, s3 = 0.f, s4 = 0.f;
    proc_nt<0>(q0,q1,q2,q3,q4,q5, a1_0,a1_1,a1_2,a1_3,
               a2_0_0,a2_0_1,a2_1_0,a2_1_1,a2_2_0,a2_2_1,a2_3_0,a2_3_1,
               w3p, g, c, srcA, srcB, hi2, s0,s1,s2,s3,s4);
    proc_nt<1>(q0,q1,q2,q3,q4,q5, a1_0,a1_1,a1_2,a1_3,
               a2_0_0,a2_0_1,a2_1_0,a2_1_1,a2_2_0,a2_2_1,a2_3_0,a2_3_1,
               w3p, g, c, srcA, srcB, hi2, s0,s1,s2,s3,s4);
    proc_nt<2>(q0,q1,q2,q3,q4,q5, a1_0,a1_1,a1_2,a1_3,
               a2_0_0,a2_0_1,a2_1_0,a2_1_1,a2_2_0,a2_2_1,a2_3_0,a2_3_1,
               w3p, g, c, srcA, srcB, hi2, s0,s1,s2,s3,s4);
    proc_nt<3>(q0,q1,q2,q3,q4,q5, a1_0,a1_1,a1_2,a1_3,
               a2_0_0,a2_0_1,a2_1_0,a2_1_1,a2_2_0,a2_2_1,a2_3_0,a2_3_1,
               w3p, g, c, srcA, srcB, hi2, s0,s1,s2,s3,s4);

    float b30 = eb3[0], b31 = eb3[1], b32 = eb3[2], b33 = eb3[3], b34 = eb3[4];
    float* row = eout + (size_t)e * 5;
    row[0] = ea_0 + b30 + s0;
    row[1] = ea_1 + b31 + s1;
    row[2] = ea_2 + b32 + s2;
    row[3] = ea_3 + b33 + s3;
    row[4] = ea_4 + b34 + s4;
}

// ---- 2-threads-per-node (wave-paired) node kernels ----
// pair: waves (2k,2k+1); h = wave&1; node local nl = (wave>>1)*64 + lane.
__global__ __launch_bounds__(256, 2)
void node_csr2(float* __restrict__ xw, const float* __restrict__ eout,
               const int* __restrict__ eidx,
               const int* __restrict__ cnt, const int* __restrict__ start,
               const float* __restrict__ nw1, const float* __restrict__ nb1,
               const float* __restrict__ nw2t, const float* __restrict__ nb2,
               const float* __restrict__ nw3, const float* __restrict__ nb3) {
    __shared__ float sg[128][16];
    int t = threadIdx.x;
    int wave = t >> 6, lane = t & 63;
    int h = wave & 1;
    int nl = (wave >> 1) * 64 + lane;
    int pid = blockIdx.x * 128 + nl;
    int i = min(pid, NN - 1);

    int nE = cnt[i];
    int base = start[i];
    int mid = (nE + 1) >> 1;
    int jlo = h ? mid : 0;
    int jhi = h ? nE : mid;

    float g0=0.f, g1=0.f, g2=0.f, g3=0.f, g4=0.f;
    int j = jlo;
    for (; j + 1 < jhi; j += 2) {
        int e0 = eidx[base + j];
        int e1 = eidx[base + j + 1];
        const float* p0 = eout + (size_t)e0 * 5;
        const float* p1 = eout + (size_t)e1 * 5;
        g0 += p0[0] + p1[0]; g1 += p0[1] + p1[1]; g2 += p0[2] + p1[2];
        g3 += p0[3] + p1[3]; g4 += p0[4] + p1[4];
    }
    if (j < jhi) {
        int e0 = eidx[base + j];
        const float* p0 = eout + (size_t)e0 * 5;
        g0 += p0[0]; g1 += p0[1]; g2 += p0[2]; g3 += p0[3]; g4 += p0[4];
    }
    sg[nl][h*8+0]=g0; sg[nl][h*8+1]=g1; sg[nl][h*8+2]=g2; sg[nl][h*8+3]=g3; sg[nl][h*8+4]=g4;
    __syncthreads();
    int p = (1-h)*8;
    g0 += sg[nl][p+0]; g1 += sg[nl][p+1]; g2 += sg[nl][p+2]; g3 += sg[nl][p+3]; g4 += sg[nl][p+4];

    float inv = 1.0f / fmaxf((float)nE, 1.0f);
    float x3v = xw[i*5+3], x4v = xw[i*5+4];

    float dphi_full;
    {
        float ein_0 = x3v;
        float ein_1 = x4v;
        float ein_2 = g0 * inv;
        float ein_3 = g1 * inv;
        float ein_4 = g2 * inv;
        float ein_5 = g3 * inv;
        float ein_6 = g4 * inv;
        R64(DECL_H1, nb1)
        R7(ROW_L1, nw1)
        R64(RELU_H1, 0)
        float dphi = h ? 0.f : nb3[0];
        for (int kb = 2*h; kb < 2*h+2; kb++) {
            const float* w2p = nw2t + kb * 1024;
            const float* b2p = nb2 + kb * 16;
            const float* w3p = nw3 + kb * 16;
            R16(DECL_A, b2p)
            R16(ROW_L2, 0)
            R16(FOLD_N, 0)
        }
        sg[nl][h*8+5] = dphi;
        __syncthreads();
        dphi_full = dphi + sg[nl][(1-h)*8+5];
    }

    if (h == 0 && pid < NN) {
        float x0=xw[i*5+0], x1=xw[i*5+1], x2=xw[i*5+2];
        float x3 = x3v, x4 = x4v + dphi_full;
        xw[i*5+0] = x0 + fmaxf(x0, 0.0f);
        xw[i*5+1] = x1 + fmaxf(x1, 0.0f);
        xw[i*5+2] = x2 + fmaxf(x2, 0.0f);
        xw[i*5+3] = x3 + fmaxf(x3, 0.0f);
        xw[i*5+4] = x4 + fmaxf(x4, 0.0f);
    }
}

__global__ __launch_bounds__(256, 2)
void node_dec2(const float* __restrict__ xw, const float* __restrict__ eout,
               const int* __restrict__ eidx,
               const int* __restrict__ cnt, const int* __restrict__ start,
               const float* __restrict__ nw1, const float* __restrict__ nb1,
               const float* __restrict__ nw2t, const float* __restrict__ nb2,
               const float* __restrict__ nw3, const float* __restrict__ nb3,
               const float* __restrict__ dw1, const float* __restrict__ db1,
               const float* __restrict__ dw2t, const float* __restrict__ db2,
               const float* __restrict__ dw3t, const float* __restrict__ db3,
               const float* __restrict__ dw4, const float* __restrict__ db4,
               float* __restrict__ out) {
    __shared__ float sg[128][16];
    __shared__ float sh2[128][65];
    int t = threadIdx.x;
    int wave = t >> 6, lane = t & 63;
    int h = wave & 1;
    int nl = (wave >> 1) * 64 + lane;
    int pid = blockIdx.x * 128 + nl;
    int i = min(pid, NN - 1);

    int nE = cnt[i];
    int base = start[i];
    int mid = (nE + 1) >> 1;
    int jlo = h ? mid : 0;
    int jhi = h ? nE : mid;

    float g0=0.f, g1=0.f, g2=0.f, g3=0.f, g4=0.f;
    int j = jlo;
    for (; j + 1 < jhi; j += 2) {
        int e0 = eidx[base + j];
        int e1 = eidx[base + j + 1];
        const float* p0 = eout + (size_t)e0 * 5;
        const float* p1 = eout + (size_t)e1 * 5;
        g0 += p0[0] + p1[0]; g1 += p0[1] + p1[1]; g2 += p0[2] + p1[2];
        g3 += p0[3] + p1[3]; g4 += p0[4] + p1[4];
    }
    if (j < jhi) {
        int e0 = eidx[base + j];
        const float* p0 = eout + (size_t)e0 * 5;
        g0 += p0[0]; g1 += p0[1]; g2 += p0[2]; g3 += p0[3]; g4 += p0[4];
    }
    sg[nl][h*8+0]=g0; sg[nl][h*8+1]=g1; sg[nl][h*8+2]=g2; sg[nl][h*8+3]=g3; sg[nl][h*8+4]=g4;
    __syncthreads();
    int p = (1-h)*8;
    g0 += sg[nl][p+0]; g1 += sg[nl][p+1]; g2 += sg[nl][p+2]; g3 += sg[nl][p+3]; g4 += sg[nl][p+4];

    float inv = 1.0f / fmaxf((float)nE, 1.0f);
    float x0=xw[i*5+0], x1=xw[i*5+1], x2=xw[i*5+2], x3=xw[i*5+3], x4=xw[i*5+4];

    float dphi_full;
    {
        float ein_0 = x3;
        float ein_1 = x4;
        float ein_2 = g0 * inv;
        float ein_3 = g1 * inv;
        float ein_4 = g2 * inv;
        float ein_5 = g3 * inv;
        float ein_6 = g4 * inv;
        R64(DECL_H1, nb1)
        R7(ROW_L1, nw1)
        R64(RELU_H1, 0)
        float dphi = h ? 0.f : nb3[0];
        for (int kb = 2*h; kb < 2*h+2; kb++) {
            const float* w2p = nw2t + kb * 1024;
            const float* b2p = nb2 + kb * 16;
            const float* w3p = nw3 + kb * 16;
            R16(DECL_A, b2p)
            R16(ROW_L2, 0)
            R16(FOLD_N, 0)
        }
        sg[nl][h*8+5] = dphi;
        __syncthreads();
        dphi_full = dphi + sg[nl][(1-h)*8+5];
    }

    x4 += dphi_full;
    float u0 = x0 + fmaxf(x0, 0.0f);
    float u1 = x1 + fmaxf(x1, 0.0f);
    float u2 = x2 + fmaxf(x2, 0.0f);
    float u3 = x3 + fmaxf(x3, 0.0f);
    float u4 = x4 + fmaxf(x4, 0.0f);

    {
        float ein_0 = u0, ein_1 = u1, ein_2 = u2, ein_3 = u3, ein_4 = u4;
        R64(DECL_H1, db1)
        R5(ROW_L1, dw1)
        R64(RELU_H1, 0)
        // L2: each half computes 2 of 4 blocks (wave-uniform weight base)
        R16(DECL_LO, 0) R16(DECL_HI, 0)
        {
            const float* w2p = dw2t + (2*h) * 1024;
            const float* b2p = db2 + (2*h) * 16;
            R16(DECL_A, b2p) R16(ROW_L2, 0) R16(ASG_LO, 0)
        }
        {
            const float* w2p = dw2t + (2*h+1) * 1024;
            const float* b2p = db2 + (2*h+1) * 16;
            R16(DECL_A, b2p) R16(ROW_L2, 0) R16(ASG_HI, 0)
        }
        float* sh2p = &sh2[nl][h*32];
        R16(ST_LO, sh2p) R16(ST_HI, sh2p)
        __syncthreads();
        const float* sh2r = &sh2[nl][0];
        R16(DECL_H2, A) R16(DECL_H2, B) R16(DECL_H2, C) R16(DECL_H2, D)
        R16(LD_H2A, sh2r) R16(LD_H2B, sh2r) R16(LD_H2C, sh2r) R16(LD_H2D, sh2r)
        // L3: each half does 2 of 4 jb blocks
        float o = h ? 0.f : db4[0];
        for (int jb2 = 2*h; jb2 < 2*h+2; jb2++) {
            const float* w3p = dw3t + jb2*1024;
            const float* b3p = db3 + jb2*16;
            const float* w4p = dw4 + jb2*16;
            R16(DECL_A, b3p)
            R16(ROW_L3, 0)
            R16(FOLD_D, 0)
        }
        sg[nl][h*8+6] = o;
        __syncthreads();
        o += sg[nl][(1-h)*8+6];
        if (h == 0 && pid < NN) out[pid] = o;
    }
}

// ---------------- fallback (atomic) kernels ----------------
__global__ void init_fb(const float* __restrict__ x, float* __restrict__ xw,
                        float* __restrict__ counts, float* __restrict__ agg) {
    int i = blockIdx.x * blockDim.x + threadIdx.x;
    if (i < NN) {
#pragma unroll
        for (int j = 0; j < 5; j++) { xw[i*5+j] = x[i*5+j]; agg[i*5+j] = 0.0f; }
        counts[i] = 0.0f;
    }
}

__global__ void count_f(const int* __restrict__ dst, float* __restrict__ counts) {
    int e = blockIdx.x * blockDim.x + threadIdx.x;
    atomicAdd(&counts[dst[e]], 1.0f);
}

__global__ __launch_bounds__(256, 2)
void edge_atomic(const float* __restrict__ xw, const float* __restrict__ edge_attr,
                 const int* __restrict__ src_idx, const int* __restrict__ dst_idx,
                 const float* __restrict__ ew1, const float* __restrict__ eb1,
                 const float* __restrict__ ew2t, const float* __restrict__ eb2,
                 const float* __restrict__ ew3, const float* __restrict__ eb3,
                 float* __restrict__ agg) {
    int e = blockIdx.x * blockDim.x + threadIdx.x;
    int s = src_idx[e];
    int d = dst_idx[e];

    float xs_0=xw[s*5+0], xs_1=xw[s*5+1], xs_2=xw[s*5+2], xs_4=xw[s*5+4];
    float xd_0=xw[d*5+0], xd_1=xw[d*5+1], xd_2=xw[d*5+2], xd_4=xw[d*5+4];
    float ea_0=edge_attr[(size_t)e*5+0], ea_1=edge_attr[(size_t)e*5+1],
          ea_2=edge_attr[(size_t)e*5+2], ea_3=edge_attr[(size_t)e*5+3],
          ea_4=edge_attr[(size_t)e*5+4];

    float ein_0 = xd_0 - xs_0;
    float ein_1 = xd_1 - xs_1;
    float ein_2 = xd_2 - xs_2;
    float ein_3 = sqrtf(ein_0*ein_0 + ein_1*ein_1 + ein_2*ein_2);
    float ein_4 = ea_0, ein_5 = ea_1, ein_6 = ea_2, ein_7 = ea_3, ein_8 = ea_4;
    float ein_9 = xs_4, ein_10 = xd_4;

    EDGE_MLP_BODY

    atomicAdd(&agg[d*5+0], ea_0 + o_0);
    atomicAdd(&agg[d*5+1], ea_1 + o_1);
    atomicAdd(&agg[d*5+2], ea_2 + o_2);
    atomicAdd(&agg[d*5+3], ea_3 + o_3);
    atomicAdd(&agg[d*5+4], ea_4 + o_4);
}

__global__ __launch_bounds__(256, 2)
void node_agg(float* __restrict__ xw, float* __restrict__ agg,
              const float* __restrict__ counts,
              const float* __restrict__ nw1, const float* __restrict__ nb1,
              const float* __restrict__ nw2t, const float* __restrict__ nb2,
              const float* __restrict__ nw3, const float* __restrict__ nb3) {
    int gid = blockIdx.x * blockDim.x + threadIdx.x;
    int i = min(gid, NN - 1);
    bool valid = (gid < NN);

    float inv = 1.0f / fmaxf(counts[i], 1.0f);
    float ein_0 = xw[i*5+3];
    float ein_1 = xw[i*5+4];
    float ein_2 = agg[i*5+0] * inv;
    float ein_3 = agg[i*5+1] * inv;
    float ein_4 = agg[i*5+2] * inv;
    float ein_5 = agg[i*5+3] * inv;
    float ein_6 = agg[i*5+4] * inv;

    NODE_MLP_BODY

    if (valid) {
        float x0=xw[i*5+0], x1=xw[i*5+1], x2=xw[i*5+2], x3=xw[i*5+3], x4=xw[i*5+4];
        x4 += dphi;
        xw[i*5+0] = x0 + fmaxf(x0, 0.0f);
        xw[i*5+1] = x1 + fmaxf(x1, 0.0f);
        xw[i*5+2] = x2 + fmaxf(x2, 0.0f);
        xw[i*5+3] = x3 + fmaxf(x3, 0.0f);
        xw[i*5+4] = x4 + fmaxf(x4, 0.0f);
        agg[i*5+0]=0.f; agg[i*5+1]=0.f; agg[i*5+2]=0.f; agg[i*5+3]=0.f; agg[i*5+4]=0.f;
    }
}

__global__ __launch_bounds__(256, 2)
void decoder_kernel(const float* __restrict__ xw,
                    const float* __restrict__ dw1, const float* __restrict__ db1,
                    const float* __restrict__ dw2t, const float* __restrict__ db2,
                    const float* __restrict__ dw3t, const float* __restrict__ db3,
                    const float* __restrict__ dw4, const float* __restrict__ db4,
                    float* __restrict__ out) {
    int gid = blockIdx.x * blockDim.x + threadIdx.x;
    int i = min(gid, NN - 1);
    bool valid = (gid < NN);

    float ein_0 = xw[i*5+0], ein_1 = xw[i*5+1], ein_2 = xw[i*5+2],
          ein_3 = xw[i*5+3], ein_4 = xw[i*5+4];

    DECODER_BODY

    if (valid) out[gid] = o;
}

extern "C" void kernel_launch(void* const* d_in, const int* in_sizes, int n_in,
                              void* d_out, int out_size, void* d_ws, size_t ws_size,
                              hipStream_t stream) {
    const float* x         = (const float*)d_in[0];
    const float* edge_attr = (const float*)d_in[1];
    const float* ew1 = (const float*)d_in[2];
    const float* eb1 = (const float*)d_in[3];
    const float* ew2 = (const float*)d_in[4];
    const float* eb2 = (const float*)d_in[5];
    const float* ew3 = (const float*)d_in[6];
    const float* eb3 = (const float*)d_in[7];
    const float* nw1 = (const float*)d_in[8];
    const float* nb1 = (const float*)d_in[9];
    const float* nw2 = (const float*)d_in[10];
    const float* nb2 = (const float*)d_in[11];
    const float* nw3 = (const float*)d_in[12];
    const float* nb3 = (const float*)d_in[13];
    const float* dw1 = (const float*)d_in[14];
    const float* db1 = (const float*)d_in[15];
    const float* dw2 = (const float*)d_in[16];
    const float* db2 = (const float*)d_in[17];
    const float* dw3 = (const float*)d_in[18];
    const float* db3 = (const float*)d_in[19];
    const float* dw4 = (const float*)d_in[20];
    const float* db4 = (const float*)d_in[21];
    const int* edge_index = (const int*)d_in[22];
    const int* src = edge_index;
    const int* dst = edge_index + NE;
    float* out = (float*)d_out;

    const size_t CSR_WS_BYTES = (size_t)10420992 * 4;

    if (ws_size >= CSR_WS_BYTES) {
        float* xw      = (float*)d_ws;
        int*   cnt     = (int*)d_ws + 500000;
        int*   start   = (int*)d_ws + 600000;
        int*   bcur    = (int*)d_ws + 700000;
        int*   bsum    = (int*)d_ws + 800000;
        int*   boff    = (int*)d_ws + 800512;
        float* nw2t    = (float*)d_ws + 805120;
        float* dw2t    = (float*)d_ws + 809216;
        float* dw3t    = (float*)d_ws + 813312;
        int*   eidx    = (int*)d_ws + 817408;
        float* eout    = (float*)d_ws + 2417408;
        int*   ebkt    = (int*)d_ws + 2417408;   // alias: dead before edge_mfma
        unsigned short* w1tb = (unsigned short*)((int*)d_ws + 10417408);
        unsigned short* w2tb = (unsigned short*)((int*)d_ws + 10418432);
        float* w3p8    = (float*)d_ws + 10420480;

        transpose64<<<64, 64, 0, stream>>>(nw2, nw2t);
        transpose64<<<64, 64, 0, stream>>>(dw2, dw2t);
        transpose64<<<64, 64, 0, stream>>>(dw3, dw3t);
        prep_wb<<<1, 256, 0, stream>>>(ew1, eb1, ew2, ew3, eb2, w1tb, w2tb, w3p8);

        init_xw<<<NGB, 256, 0, stream>>>(x, xw, bsum, bcur);
        bhist_kernel<<<250, 256, 0, stream>>>(dst, bsum);
        scanb_kernel<<<1, 512, 0, stream>>>(bsum, boff);
        sort_pass1<<<250, 256, 0, stream>>>(dst, boff, bcur, ebkt);
        sort_pass2<<<NBKT, 256, 0, stream>>>(ebkt, dst, boff, bsum, eidx, cnt, start);

        // iteration 1
        edge_mfma<<<NE/256, 256, 0, stream>>>(xw, edge_attr, src, dst,
                                              w1tb, w2tb, w3p8, eb3, eout);
        node_csr2<<<NB2, 256, 0, stream>>>(xw, eout, eidx, cnt, start,
                                           nw1, nb1, nw2t, nb2, nw3, nb3);
        // iteration 2 (node fused with decoder)
        edge_mfma<<<NE/256, 256, 0, stream>>>(xw, edge_attr, src, dst,
                                              w1tb, w2tb, w3p8, eb3, eout);
        node_dec2<<<NB2, 256, 0, stream>>>(xw, eout, eidx, cnt, start,
                                           nw1, nb1, nw2t, nb2, nw3, nb3,
                                           dw1, db1, dw2t, db2, dw3t, db3, dw4, db4,
                                           out);
    } else {
        float* xw     = (float*)d_ws;
        float* counts = (float*)d_ws + 500000;
        float* agg    = (float*)d_ws + 600000;
        float* ew2t  = (float*)d_ws + 1100000;
        float* nw2t   = (float*)d_ws + 1104096;
        float* dw2t   = (float*)d_ws + 1108192;
        float* dw3t   = (float*)d_ws + 1112288;

        transpose64<<<64, 64, 0, stream>>>(ew2, ew2t);
        transpose64<<<64, 64, 0, stream>>>(nw2, nw2t);
        transpose64<<<64, 64, 0, stream>>>(dw2, dw2t);
        transpose64<<<64, 64, 0, stream>>>(dw3, dw3t);

        init_fb<<<NGB, 256, 0, stream>>>(x, xw, counts, agg);
        count_f<<<NE/256, 256, 0, stream>>>(dst, counts);

        for (int it = 0; it < 2; it++) {
            edge_atomic<<<NE/256, 256, 0, stream>>>(xw, edge_attr, src, dst,
                                                    ew1, eb1, ew2t, eb2, ew3, eb3, agg);
            node_agg<<<NGB, 256, 0, stream>>>(xw, agg, counts,
                                              nw1, nb1, nw2t, nb2, nw3, nb3);
        }
        decoder_kernel<<<NGB, 256, 0, stream>>>(xw, dw1, db1, dw2t, db2,
                                                dw3t, db3, dw4, db4, out);
    }
}

// Round 19
// 441.356 us; speedup vs baseline: 1.2431x; 1.2431x over previous
//
#include <hip/hip_runtime.h>
#include <math.h>

#define NN 100000
#define NE 1600000
#define NGB 391   // (NN+255)/256 = buckets of 256 nodes
#define NBKT 391

// ================= MFMA types =================
typedef __attribute__((ext_vector_type(8))) __bf16 bf16x8;
typedef __attribute__((ext_vector_type(4))) float f32x4;
union FR { unsigned u[4]; bf16x8 v; };

__device__ __forceinline__ f32x4 MFMA(bf16x8 a, bf16x8 b, f32x4 c) {
    return __builtin_amdgcn_mfma_f32_16x16x32_bf16(a, b, c, 0, 0, 0);
}
__device__ __forceinline__ unsigned pk2(float lo, float hi) {
    union { __bf16 b[2]; unsigned u; } P;
    P.b[0] = (__bf16)lo; P.b[1] = (__bf16)hi;
    return P.u;
}

// ---------------- repetition macros ----------------
#define R5(M,A)  M(0,A) M(1,A) M(2,A) M(3,A) M(4,A)
#define R7(M,A)  M(0,A) M(1,A) M(2,A) M(3,A) M(4,A) M(5,A) M(6,A)
#define R11(M,A) R7(M,A) M(7,A) M(8,A) M(9,A) M(10,A)
#define R16(M,A) M(0,A) M(1,A) M(2,A) M(3,A) M(4,A) M(5,A) M(6,A) M(7,A) \
                 M(8,A) M(9,A) M(10,A) M(11,A) M(12,A) M(13,A) M(14,A) M(15,A)
#define R16I(M,A) M(0,A) M(1,A) M(2,A) M(3,A) M(4,A) M(5,A) M(6,A) M(7,A) \
                  M(8,A) M(9,A) M(10,A) M(11,A) M(12,A) M(13,A) M(14,A) M(15,A)
#define R64(M,A) \
  M(0,A) M(1,A) M(2,A) M(3,A) M(4,A) M(5,A) M(6,A) M(7,A) \
  M(8,A) M(9,A) M(10,A) M(11,A) M(12,A) M(13,A) M(14,A) M(15,A) \
  M(16,A) M(17,A) M(18,A) M(19,A) M(20,A) M(21,A) M(22,A) M(23,A) \
  M(24,A) M(25,A) M(26,A) M(27,A) M(28,A) M(29,A) M(30,A) M(31,A) \
  M(32,A) M(33,A) M(34,A) M(35,A) M(36,A) M(37,A) M(38,A) M(39,A) \
  M(40,A) M(41,A) M(42,A) M(43,A) M(44,A) M(45,A) M(46,A) M(47,A) \
  M(48,A) M(49,A) M(50,A) M(51,A) M(52,A) M(53,A) M(54,A) M(55,A) \
  M(56,A) M(57,A) M(58,A) M(59,A) M(60,A) M(61,A) M(62,A) M(63,A)

#define DECL_H1(J,P) float h1_##J = (P)[J];
#define FMA_L1(J,K)  h1_##J = fmaf(ein_##K, wrow[J], h1_##J);
#define ROW_L1(K,W)  { const float* wrow = (W) + (K)*64; R64(FMA_L1,K) }
#define RELU_H1(J,A) h1_##J = fmaxf(h1_##J, 0.0f);
#define DECL_A(K,P)  float a_##K = (P)[K];
#define FMA_L2(Q,K)  a_##K = fmaf(h1_##Q, w2p[(K)*64+Q], a_##K);
#define ROW_L2(K,A)  R64(FMA_L2,K)
#define FOLD_E(K,A) { float r = fmaxf(a_##K, 0.0f); \
  o_0 = fmaf(r, w3p[(K)*5+0], o_0); o_1 = fmaf(r, w3p[(K)*5+1], o_1); \
  o_2 = fmaf(r, w3p[(K)*5+2], o_2); o_3 = fmaf(r, w3p[(K)*5+3], o_3); \
  o_4 = fmaf(r, w3p[(K)*5+4], o_4); }
#define FOLD_N(K,A)  dphi = fmaf(fmaxf(a_##K, 0.0f), w3p[K], dphi);
#define DECL_H2(K,G) float h2##G##_##K;
#define ASG_H2(K,G)  h2##G##_##K = fmaxf(a_##K, 0.0f);
#define L2BLK(G,B)   { const float* w2p = dw2t + (B)*1024; const float* b2p = db2 + (B)*16; \
                       R16(DECL_A,b2p) R16(ROW_L2,0) R16(ASG_H2,G) }
#define FMA_L3A(Q,K) a_##K = fmaf(h2A_##Q, w3p[(K)*64+Q],    a_##K);
#define FMA_L3B(Q,K) a_##K = fmaf(h2B_##Q, w3p[(K)*64+16+Q], a_##K);
#define FMA_L3C(Q,K) a_##K = fmaf(h2C_##Q, w3p[(K)*64+32+Q], a_##K);
#define FMA_L3D(Q,K) a_##K = fmaf(h2D_##Q, w3p[(K)*64+48+Q], a_##K);
#define ROW_L3(K,A)  R16I(FMA_L3A,K) R16I(FMA_L3B,K) R16I(FMA_L3C,K) R16I(FMA_L3D,K)
#define FOLD_D(K,A)  o = fmaf(fmaxf(a_##K, 0.0f), w4p[K], o);

#define EDGE_MLP_BODY \
    R64(DECL_H1, eb1) \
    R11(ROW_L1, ew1) \
    R64(RELU_H1, 0) \
    float o_0=eb3[0], o_1=eb3[1], o_2=eb3[2], o_3=eb3[3], o_4=eb3[4]; \
    for (int kb = 0; kb < 4; kb++) { \
        const float* w2p = ew2t + kb * 1024; \
        const float* b2p = eb2 + kb * 16; \
        const float* w3p = ew3 + kb * 80; \
        R16(DECL_A, b2p) \
        R16(ROW_L2, 0) \
        R16(FOLD_E, 0) \
    }

#define NODE_MLP_BODY \
    R64(DECL_H1, nb1) \
    R7(ROW_L1, nw1) \
    R64(RELU_H1, 0) \
    float dphi = nb3[0]; \
    for (int kb = 0; kb < 4; kb++) { \
        const float* w2p = nw2t + kb * 1024; \
        const float* b2p = nb2 + kb * 16; \
        const float* w3p = nw3 + kb * 16; \
        R16(DECL_A, b2p) \
        R16(ROW_L2, 0) \
        R16(FOLD_N, 0) \
    }

#define DECODER_BODY \
    R64(DECL_H1, db1) \
    R5(ROW_L1, dw1) \
    R64(RELU_H1, 0) \
    R16(DECL_H2, A) R16(DECL_H2, B) R16(DECL_H2, C) R16(DECL_H2, D) \
    L2BLK(A, 0) L2BLK(B, 1) L2BLK(C, 2) L2BLK(D, 3) \
    float o = db4[0]; \
    for (int jb = 0; jb < 4; jb++) { \
        const float* w3p = dw3t + jb*1024; \
        const float* b3p = db3 + jb*16; \
        const float* w4p = dw4 + jb*16; \
        R16(DECL_A, b3p) \
        R16(ROW_L3, 0) \
        R16(FOLD_D, 0) \
    }

// ---------------- small utility kernels ----------------
__global__ void transpose64(const float* __restrict__ in, float* __restrict__ out) {
    int j = blockIdx.x, k = threadIdx.x;
    out[j * 64 + k] = in[k * 64 + j];
}

__global__ void prep_wb(const float* __restrict__ ew1, const float* __restrict__ eb1,
                        const float* __restrict__ ew2,
                        const float* __restrict__ ew3, const float* __restrict__ eb2,
                        unsigned short* __restrict__ w1t, unsigned short* __restrict__ w2t,
                        float* __restrict__ w3p) {
    int t = threadIdx.x;
    for (int idx = t; idx < 64*32; idx += 256) {
        int m = idx >> 5, k = idx & 31;
        float v = (k < 11) ? ew1[k*64 + m] : (k == 11 ? eb1[m] : 0.0f);
        union { __bf16 b; unsigned short u; } U; U.b = (__bf16)v;
        w1t[idx] = U.u;
    }
    for (int idx = t; idx < 64*64; idx += 256) {
        int m = idx >> 6, k = idx & 63;
        union { __bf16 b; unsigned short u; } U; U.b = (__bf16)(ew2[k*64 + m]);
        w2t[idx] = U.u;
    }
    for (int idx = t; idx < 64*8; idx += 256) {
        int F = idx >> 3, j = idx & 7;
        w3p[idx] = (j < 5) ? ew3[F*5 + j] : (j == 5 ? eb2[F] : 0.0f);
    }
}

__global__ void init_xw(const float* __restrict__ x, float* __restrict__ xw,
                        int* __restrict__ bsum, int* __restrict__ bcur) {
    int i = blockIdx.x * blockDim.x + threadIdx.x;
    if (i < NN) {
#pragma unroll
        for (int j = 0; j < 5; j++) xw[i*5+j] = x[i*5+j];
    }
    if (i < 512) bsum[i] = 0;
    if (i < NBKT) bcur[i] = 0;
}

__global__ __launch_bounds__(256)
void bhist_kernel(const int* __restrict__ dst, int* __restrict__ bsum) {
    __shared__ int h[NBKT];
    int t = threadIdx.x;
    for (int i = t; i < NBKT; i += 256) h[i] = 0;
    __syncthreads();
    int eb = blockIdx.x * 6400;
#pragma unroll
    for (int it = 0; it < 25; ++it) {
        int e = eb + it*256 + t;
        atomicAdd(&h[dst[e] >> 8], 1);
    }
    __syncthreads();
    for (int i = t; i < NBKT; i += 256)
        if (h[i]) atomicAdd(&bsum[i], h[i]);
}

__global__ void scanb_kernel(const int* __restrict__ bsum, int* __restrict__ boff) {
    __shared__ int s[512];
    int t = threadIdx.x;
    int v0 = (t < NGB) ? bsum[t] : 0;
    s[t] = v0;
    __syncthreads();
    for (int o = 1; o < 512; o <<= 1) {
        int v = (t >= o) ? s[t - o] : 0;
        __syncthreads();
        s[t] += v;
        __syncthreads();
    }
    if (t < NGB) boff[t] = s[t] - v0;   // exclusive
}

__global__ __launch_bounds__(256)
void sort_pass1(const int* __restrict__ dst, const int* __restrict__ boff,
                int* __restrict__ bcur, int* __restrict__ ebkt) {
    __shared__ int hist[NBKT];
    __shared__ int s[512];
    __shared__ int scanBase[NBKT];
    __shared__ int cur[NBKT];
    __shared__ int gbase[NBKT];
    __shared__ int stage[6400];
    int t = threadIdx.x;
    int eb = blockIdx.x * 6400;

    for (int i = t; i < NBKT; i += 256) hist[i] = 0;
    __syncthreads();
#pragma unroll
    for (int it = 0; it < 25; ++it) {
        int e = eb + it*256 + t;
        atomicAdd(&hist[dst[e] >> 8], 1);
    }
    __syncthreads();
    s[t]       = (t < NBKT) ? hist[t] : 0;
    s[t + 256] = (t + 256 < NBKT) ? hist[t + 256] : 0;
    __syncthreads();
    for (int o = 1; o < 512; o <<= 1) {
        int v0 = (t >= o) ? s[t - o] : 0;
        int v1 = ((t + 256) >= o) ? s[t + 256 - o] : 0;
        __syncthreads();
        s[t] += v0; s[t + 256] += v1;
        __syncthreads();
    }
    for (int i = t; i < NBKT; i += 256) {
        int ex = s[i] - hist[i];
        scanBase[i] = ex;
        cur[i] = ex;
        gbase[i] = (hist[i] > 0) ? atomicAdd(&bcur[i], hist[i]) : 0;
    }
    __syncthreads();
#pragma unroll
    for (int it = 0; it < 25; ++it) {
        int e = eb + it*256 + t;
        int b = dst[e] >> 8;
        int ls = atomicAdd(&cur[b], 1);
        stage[ls] = (b << 21) | e;
    }
    __syncthreads();
#pragma unroll
    for (int it = 0; it < 25; ++it) {
        int k = it*256 + t;
        int p = stage[k];
        int b = p >> 21;
        int e = p & 0x1FFFFF;
        ebkt[boff[b] + gbase[b] + (k - scanBase[b])] = e;
    }
}

__global__ __launch_bounds__(256)
void sort_pass2(const int* __restrict__ ebkt, const int* __restrict__ dst,
                const int* __restrict__ boff, const int* __restrict__ bsum,
                int* __restrict__ eidx, int* __restrict__ cnt, int* __restrict__ start) {
    __shared__ int ncnt[256];
    __shared__ int s[256];
    __shared__ int lbase[256];
    __shared__ int lcur[256];
    __shared__ int outst[6144];
    int b = blockIdx.x, t = threadIdx.x;
    int node0 = b << 8;
    int nb = bsum[b];
    int base = boff[b];

    ncnt[t] = 0;
    __syncthreads();
    for (int k = t; k < nb; k += 256) {
        int e = ebkt[base + k];
        atomicAdd(&ncnt[dst[e] - node0], 1);
    }
    __syncthreads();
    int c = ncnt[t];
    s[t] = c;
    __syncthreads();
    for (int o = 1; o < 256; o <<= 1) {
        int v = (t >= o) ? s[t - o] : 0;
        __syncthreads();
        s[t] += v;
        __syncthreads();
    }
    lbase[t] = s[t] - c;
    lcur[t] = 0;
    __syncthreads();
    for (int k = t; k < nb; k += 256) {
        int e = ebkt[base + k];
        int dl = dst[e] - node0;
        int ls = lbase[dl] + atomicAdd(&lcur[dl], 1);
        outst[ls] = e;
    }
    __syncthreads();
    for (int k = t; k < nb; k += 256) eidx[base + k] = outst[k];
    int i = node0 + t;
    if (i < NN) { cnt[i] = c; start[i] = base + lbase[t]; }
}

// ---------------- MFMA edge kernel ----------------
#define EPI1(MT,RR,C2) { \
    int F = (MT)*16 + 4*g + (RR); \
    const float4* wq = reinterpret_cast<const float4*>(w3p + F*8); \
    float4 wA = wq[0]; float4 wB = wq[1]; \
    float hh = fmaxf(C2[RR] + wB.y, 0.f); \
    o0=fmaf(hh,wA.x,o0); o1=fmaf(hh,wA.y,o1); o2=fmaf(hh,wA.z,o2); \
    o3=fmaf(hh,wA.w,o3); o4=fmaf(hh,wB.x,o4); }

template<int NT>
__device__ __forceinline__ void proc_nt(
    unsigned q0, unsigned q1, unsigned q2, unsigned q3, unsigned q4, unsigned q5,
    FR a1_0, FR a1_1, FR a1_2, FR a1_3,
    FR a2_00, FR a2_01, FR a2_10, FR a2_11,
    FR a2_20, FR a2_21, FR a2_30, FR a2_31,
    const float* __restrict__ w3p,
    int g, int c, int srcA, int srcB, bool hi2,
    float& s0, float& s1, float& s2, float& s3, float& s4)
{
    f32x4 z = {0.f, 0.f, 0.f, 0.f};

    int srcl = NT*16 + c;
    unsigned m0=__shfl(q0,srcl), m1=__shfl(q1,srcl), m2=__shfl(q2,srcl);
    unsigned m3=__shfl(q3,srcl), m4=__shfl(q4,srcl), m5=__shfl(q5,srcl);
    FR B;
    B.u[0] = (g==0)?m0:((g==1)?m4:0u);
    B.u[1] = (g==0)?m1:((g==1)?m5:0u);
    B.u[2] = (g==0)?m2:0u;
    B.u[3] = (g==0)?m3:0u;
    f32x4 c1_0 = MFMA(a1_0.v, B.v, z);
    f32x4 c1_1 = MFMA(a1_1.v, B.v, z);
    f32x4 c1_2 = MFMA(a1_2.v, B.v, z);
    f32x4 c1_3 = MFMA(a1_3.v, B.v, z);

    unsigned pk01_0 = pk2(fmaxf(c1_0[0],0.f), fmaxf(c1_0[1],0.f));
    unsigned pk23_0 = pk2(fmaxf(c1_0[2],0.f), fmaxf(c1_0[3],0.f));
    unsigned pk01_1 = pk2(fmaxf(c1_1[0],0.f), fmaxf(c1_1[1],0.f));
    unsigned pk23_1 = pk2(fmaxf(c1_1[2],0.f), fmaxf(c1_1[3],0.f));
    unsigned pk01_2 = pk2(fmaxf(c1_2[0],0.f), fmaxf(c1_2[1],0.f));
    unsigned pk23_2 = pk2(fmaxf(c1_2[2],0.f), fmaxf(c1_2[3],0.f));
    unsigned pk01_3 = pk2(fmaxf(c1_3[0],0.f), fmaxf(c1_3[1],0.f));
    unsigned pk23_3 = pk2(fmaxf(c1_3[2],0.f), fmaxf(c1_3[3],0.f));

    FR B20;
    {
        unsigned sA0=__shfl(pk01_0,srcA), sA1=__shfl(pk01_1,srcA);
        unsigned sB0=__shfl(pk23_0,srcA), sB1=__shfl(pk23_1,srcA);
        unsigned sC0=__shfl(pk01_0,srcB), sC1=__shfl(pk01_1,srcB);
        unsigned sD0=__shfl(pk23_0,srcB), sD1=__shfl(pk23_1,srcB);
        B20.u[0]=hi2?sA1:sA0; B20.u[1]=hi2?sB1:sB0;
        B20.u[2]=hi2?sC1:sC0; B20.u[3]=hi2?sD1:sD0;
    }
    FR B21;
    {
        unsigned sA0=__shfl(pk01_2,srcA), sA1=__shfl(pk01_3,srcA);
        unsigned sB0=__shfl(pk23_2,srcA), sB1=__shfl(pk23_3,srcA);
        unsigned sC0=__shfl(pk01_2,srcB), sC1=__shfl(pk01_3,srcB);
        unsigned sD0=__shfl(pk23_2,srcB), sD1=__shfl(pk23_3,srcB);
        B21.u[0]=hi2?sA1:sA0; B21.u[1]=hi2?sB1:sB0;
        B21.u[2]=hi2?sC1:sC0; B21.u[3]=hi2?sD1:sD0;
    }
    f32x4 c2_0 = MFMA(a2_00.v, B20.v, z);   c2_0 = MFMA(a2_01.v, B21.v, c2_0);
    f32x4 c2_1 = MFMA(a2_10.v, B20.v, z);   c2_1 = MFMA(a2_11.v, B21.v, c2_1);
    f32x4 c2_2 = MFMA(a2_20.v, B20.v, z);   c2_2 = MFMA(a2_21.v, B21.v, c2_2);
    f32x4 c2_3 = MFMA(a2_30.v, B20.v, z);   c2_3 = MFMA(a2_31.v, B21.v, c2_3);

    float o0=0.f, o1=0.f, o2=0.f, o3=0.f, o4=0.f;
    EPI1(0,0,c2_0) EPI1(0,1,c2_0) EPI1(0,2,c2_0) EPI1(0,3,c2_0)
    EPI1(1,0,c2_1) EPI1(1,1,c2_1) EPI1(1,2,c2_1) EPI1(1,3,c2_1)
    EPI1(2,0,c2_2) EPI1(2,1,c2_2) EPI1(2,2,c2_2) EPI1(2,3,c2_2)
    EPI1(3,0,c2_3) EPI1(3,1,c2_3) EPI1(3,2,c2_3) EPI1(3,3,c2_3)

    o0 += __shfl_xor(o0,16); o0 += __shfl_xor(o0,32);
    o1 += __shfl_xor(o1,16); o1 += __shfl_xor(o1,32);
    o2 += __shfl_xor(o2,16); o2 += __shfl_xor(o2,32);
    o3 += __shfl_xor(o3,16); o3 += __shfl_xor(o3,32);
    o4 += __shfl_xor(o4,16); o4 += __shfl_xor(o4,32);

    if (g == NT) { s0 = o0; s1 = o1; s2 = o2; s3 = o3; s4 = o4; }
}

#define LOAD_A1(MT) FR a1_##MT; \
    *reinterpret_cast<uint4*>(a1_##MT.u) = \
        *reinterpret_cast<const uint4*>(w1t + ((MT)*16 + c)*32 + 8*g);
#define LOAD_A2(MT) FR a2_##MT##_0, a2_##MT##_1; \
    *reinterpret_cast<uint4*>(a2_##MT##_0.u) = \
        *reinterpret_cast<const uint4*>(w2t + ((MT)*16 + c)*64 + 8*g); \
    *reinterpret_cast<uint4*>(a2_##MT##_1.u) = \
        *reinterpret_cast<const uint4*>(w2t + ((MT)*16 + c)*64 + 32 + 8*g);

__global__ __launch_bounds__(256, 4)
void edge_mfma(const float* __restrict__ xw, const float* __restrict__ edge_attr,
               const int* __restrict__ src_idx, const int* __restrict__ dst_idx,
               const unsigned short* __restrict__ w1t, const unsigned short* __restrict__ w2t,
               const float* __restrict__ w3p, const float* __restrict__ eb3,
               float* __restrict__ eout) {
    int tid = threadIdx.x;
    int l = tid & 63;
    int g = l >> 4;
    int c = l & 15;
    int e = blockIdx.x * 256 + tid;

    int s = src_idx[e];
    int d = dst_idx[e];
    float xs_0=xw[s*5+0], xs_1=xw[s*5+1], xs_2=xw[s*5+2], xs_4=xw[s*5+4];
    float xd_0=xw[d*5+0], xd_1=xw[d*5+1], xd_2=xw[d*5+2], xd_4=xw[d*5+4];
    float ea_0=edge_attr[(size_t)e*5+0], ea_1=edge_attr[(size_t)e*5+1],
          ea_2=edge_attr[(size_t)e*5+2], ea_3=edge_attr[(size_t)e*5+3],
          ea_4=edge_attr[(size_t)e*5+4];

    float ein_0 = xd_0 - xs_0;
    float ein_1 = xd_1 - xs_1;
    float ein_2 = xd_2 - xs_2;
    float ein_3 = sqrtf(ein_0*ein_0 + ein_1*ein_1 + ein_2*ein_2);

    unsigned q0 = pk2(ein_0, ein_1);
    unsigned q1 = pk2(ein_2, ein_3);
    unsigned q2 = pk2(ea_0, ea_1);
    unsigned q3 = pk2(ea_2, ea_3);
    unsigned q4 = pk2(ea_4, xs_4);
    unsigned q5 = pk2(xd_4, 1.0f);

    LOAD_A1(0) LOAD_A1(1) LOAD_A1(2) LOAD_A1(3)
    LOAD_A2(0) LOAD_A2(1) LOAD_A2(2) LOAD_A2(3)

    int srcA = (g & 1) * 32 + c;
    int srcB = srcA + 16;
    bool hi2 = (g & 2) != 0;

    float s0 = 0.f, s1 = 0.f, s2 = 0.f, s3 = 0.f, s4 = 0.f;
    proc_nt<0>(q0,q1,q2,q3,q4,q5, a1_0,a1_1,a1_2,a1_3,
               a2_0_0,a2_0_1,a2_1_0,a2_1_1,a2_2_0,a2_2_1,a2_3_0,a2_3_1,
               w3p, g, c, srcA, srcB, hi2, s0,s1,s2,s3,s4);
    proc_nt<1>(q0,q1,q2,q3,q4,q5, a1_0,a1_1,a1_2,a1_3,
               a2_0_0,a2_0_1,a2_1_0,a2_1_1,a2_2_0,a2_2_1,a2_3_0,a2_3_1,
               w3p, g, c, srcA, srcB, hi2, s0,s1,s2,s3,s4);
    proc_nt<2>(q0,q1,q2,q3,q4,q5, a1_0,a1_1,a1_2,a1_3,
               a2_0_0,a2_0_1,a2_1_0,a2_1_1,a2_2_0,a2_2_1,a2_3_0,a2_3_1,
               w3p, g, c, srcA, srcB, hi2, s0,s1,s2,s3,s4);
    proc_nt<3>(q0,q1,q2,q3,q4,q5, a1_0,a1_1,a1_2,a1_3,
               a2_0_0,a2_0_1,a2_1_0,a2_1_1,a2_2_0,a2_2_1,a2_3_0,a2_3_1,
               w3p, g, c, srcA, srcB, hi2, s0,s1,s2,s3,s4);

    float b30 = eb3[0], b31 = eb3[1], b32 = eb3[2], b33 = eb3[3], b34 = eb3[4];
    float* row = eout + (size_t)e * 5;
    row[0] = ea_0 + b30 + s0;
    row[1] = ea_1 + b31 + s1;
    row[2] = ea_2 + b32 + s2;
    row[3] = ea_3 + b33 + s3;
    row[4] = ea_4 + b34 + s4;
}

// ---------------- scalar node kernels (round-15, tier 2) ----------------
__global__ __launch_bounds__(256, 2)
void node_csr(float* __restrict__ xw, const float* __restrict__ eout,
              const int* __restrict__ eidx,
              const int* __restrict__ cnt, const int* __restrict__ start,
              const float* __restrict__ nw1, const float* __restrict__ nb1,
              const float* __restrict__ nw2t, const float* __restrict__ nb2,
              const float* __restrict__ nw3, const float* __restrict__ nb3) {
    int gid = blockIdx.x * blockDim.x + threadIdx.x;
    int i = min(gid, NN - 1);
    bool valid = (gid < NN);

    int nE = cnt[i];
    int base = start[i];
    float g0=0.f, g1=0.f, g2=0.f, g3=0.f, g4=0.f;
    int j = 0;
    for (; j + 1 < nE; j += 2) {
        int e0 = eidx[base + j];
        int e1 = eidx[base + j + 1];
        const float* p0 = eout + (size_t)e0 * 5;
        const float* p1 = eout + (size_t)e1 * 5;
        g0 += p0[0] + p1[0]; g1 += p0[1] + p1[1]; g2 += p0[2] + p1[2];
        g3 += p0[3] + p1[3]; g4 += p0[4] + p1[4];
    }
    if (j < nE) {
        int e0 = eidx[base + j];
        const float* p0 = eout + (size_t)e0 * 5;
        g0 += p0[0]; g1 += p0[1]; g2 += p0[2]; g3 += p0[3]; g4 += p0[4];
    }
    float inv = 1.0f / fmaxf((float)nE, 1.0f);

    float ein_0 = xw[i*5+3];
    float ein_1 = xw[i*5+4];
    float ein_2 = g0 * inv;
    float ein_3 = g1 * inv;
    float ein_4 = g2 * inv;
    float ein_5 = g3 * inv;
    float ein_6 = g4 * inv;

    NODE_MLP_BODY

    if (valid) {
        float x0=xw[i*5+0], x1=xw[i*5+1], x2=xw[i*5+2], x3=xw[i*5+3], x4=xw[i*5+4];
        x4 += dphi;
        xw[i*5+0] = x0 + fmaxf(x0, 0.0f);
        xw[i*5+1] = x1 + fmaxf(x1, 0.0f);
        xw[i*5+2] = x2 + fmaxf(x2, 0.0f);
        xw[i*5+3] = x3 + fmaxf(x3, 0.0f);
        xw[i*5+4] = x4 + fmaxf(x4, 0.0f);
    }
}

__global__ __launch_bounds__(256, 2)
void node_dec(const float* __restrict__ xw, const float* __restrict__ eout,
              const int* __restrict__ eidx,
              const int* __restrict__ cnt, const int* __restrict__ start,
              const float* __restrict__ nw1, const float* __restrict__ nb1,
              const float* __restrict__ nw2t, const float* __restrict__ nb2,
              const float* __restrict__ nw3, const float* __restrict__ nb3,
              const float* __restrict__ dw1, const float* __restrict__ db1,
              const float* __restrict__ dw2t, const float* __restrict__ db2,
              const float* __restrict__ dw3t, const float* __restrict__ db3,
              const float* __restrict__ dw4, const float* __restrict__ db4,
              float* __restrict__ out) {
    int gid = blockIdx.x * blockDim.x + threadIdx.x;
    int i = min(gid, NN - 1);
    bool valid = (gid < NN);

    int nE = cnt[i];
    int base = start[i];
    float g0=0.f, g1=0.f, g2=0.f, g3=0.f, g4=0.f;
    int j = 0;
    for (; j + 1 < nE; j += 2) {
        int e0 = eidx[base + j];
        int e1 = eidx[base + j + 1];
        const float* p0 = eout + (size_t)e0 * 5;
        const float* p1 = eout + (size_t)e1 * 5;
        g0 += p0[0] + p1[0]; g1 += p0[1] + p1[1]; g2 += p0[2] + p1[2];
        g3 += p0[3] + p1[3]; g4 += p0[4] + p1[4];
    }
    if (j < nE) {
        int e0 = eidx[base + j];
        const float* p0 = eout + (size_t)e0 * 5;
        g0 += p0[0]; g1 += p0[1]; g2 += p0[2]; g3 += p0[3]; g4 += p0[4];
    }
    float inv = 1.0f / fmaxf((float)nE, 1.0f);

    float x0=xw[i*5+0], x1=xw[i*5+1], x2=xw[i*5+2], x3=xw[i*5+3], x4=xw[i*5+4];

    float dphi_out;
    {
        float ein_0 = x3;
        float ein_1 = x4;
        float ein_2 = g0 * inv;
        float ein_3 = g1 * inv;
        float ein_4 = g2 * inv;
        float ein_5 = g3 * inv;
        float ein_6 = g4 * inv;
        NODE_MLP_BODY
        dphi_out = dphi;
    }

    x4 += dphi_out;
    float u0 = x0 + fmaxf(x0, 0.0f);
    float u1 = x1 + fmaxf(x1, 0.0f);
    float u2 = x2 + fmaxf(x2, 0.0f);
    float u3 = x3 + fmaxf(x3, 0.0f);
    float u4 = x4 + fmaxf(x4, 0.0f);

    {
        float ein_0 = u0, ein_1 = u1, ein_2 = u2, ein_3 = u3, ein_4 = u4;
        DECODER_BODY
        if (valid) out[gid] = o;
    }
}

// ---------------- tier-1: parallel gather + MLP-only node kernels -----------
__global__ __launch_bounds__(256)
void gather4(const float* __restrict__ eout, const int* __restrict__ eidx,
             const int* __restrict__ cnt, const int* __restrict__ start,
             float* __restrict__ agg) {
    int gid = blockIdx.x * 256 + threadIdx.x;
    int node = gid >> 2;
    int sub = gid & 3;
    int i = min(node, NN - 1);
    int nE = cnt[i];
    int base = start[i];
    float g0=0.f, g1=0.f, g2=0.f, g3=0.f, g4=0.f;
    for (int j = sub; j < nE; j += 4) {
        int e0 = eidx[base + j];
        const float* p = eout + (size_t)e0 * 5;
        g0 += p[0]; g1 += p[1]; g2 += p[2]; g3 += p[3]; g4 += p[4];
    }
    g0 += __shfl_xor(g0, 1); g0 += __shfl_xor(g0, 2);
    g1 += __shfl_xor(g1, 1); g1 += __shfl_xor(g1, 2);
    g2 += __shfl_xor(g2, 1); g2 += __shfl_xor(g2, 2);
    g3 += __shfl_xor(g3, 1); g3 += __shfl_xor(g3, 2);
    g4 += __shfl_xor(g4, 1); g4 += __shfl_xor(g4, 2);
    if (sub == 0 && node < NN) {
        agg[(size_t)node*5+0] = g0;
        agg[(size_t)node*5+1] = g1;
        agg[(size_t)node*5+2] = g2;
        agg[(size_t)node*5+3] = g3;
        agg[(size_t)node*5+4] = g4;
    }
}

__global__ __launch_bounds__(256, 2)
void nodeA(float* __restrict__ xw, const float* __restrict__ agg,
           const int* __restrict__ cnt,
           const float* __restrict__ nw1, const float* __restrict__ nb1,
           const float* __restrict__ nw2t, const float* __restrict__ nb2,
           const float* __restrict__ nw3, const float* __restrict__ nb3) {
    int gid = blockIdx.x * blockDim.x + threadIdx.x;
    int i = min(gid, NN - 1);
    bool valid = (gid < NN);

    float inv = 1.0f / fmaxf((float)cnt[i], 1.0f);
    float ein_0 = xw[i*5+3];
    float ein_1 = xw[i*5+4];
    float ein_2 = agg[(size_t)i*5+0] * inv;
    float ein_3 = agg[(size_t)i*5+1] * inv;
    float ein_4 = agg[(size_t)i*5+2] * inv;
    float ein_5 = agg[(size_t)i*5+3] * inv;
    float ein_6 = agg[(size_t)i*5+4] * inv;

    NODE_MLP_BODY

    if (valid) {
        float x0=xw[i*5+0], x1=xw[i*5+1], x2=xw[i*5+2], x3=xw[i*5+3], x4=xw[i*5+4];
        x4 += dphi;
        xw[i*5+0] = x0 + fmaxf(x0, 0.0f);
        xw[i*5+1] = x1 + fmaxf(x1, 0.0f);
        xw[i*5+2] = x2 + fmaxf(x2, 0.0f);
        xw[i*5+3] = x3 + fmaxf(x3, 0.0f);
        xw[i*5+4] = x4 + fmaxf(x4, 0.0f);
    }
}

__global__ __launch_bounds__(256, 2)
void nodeB(const float* __restrict__ xw, const float* __restrict__ agg,
           const int* __restrict__ cnt,
           const float* __restrict__ nw1, const float* __restrict__ nb1,
           const float* __restrict__ nw2t, const float* __restrict__ nb2,
           const float* __restrict__ nw3, const float* __restrict__ nb3,
           const float* __restrict__ dw1, const float* __restrict__ db1,
           const float* __restrict__ dw2t, const float* __restrict__ db2,
           const float* __restrict__ dw3t, const float* __restrict__ db3,
           const float* __restrict__ dw4, const float* __restrict__ db4,
           float* __restrict__ out) {
    int gid = blockIdx.x * blockDim.x + threadIdx.x;
    int i = min(gid, NN - 1);
    bool valid = (gid < NN);

    float inv = 1.0f / fmaxf((float)cnt[i], 1.0f);
    float x0=xw[i*5+0], x1=xw[i*5+1], x2=xw[i*5+2], x3=xw[i*5+3], x4=xw[i*5+4];

    float dphi_out;
    {
        float ein_0 = x3;
        float ein_1 = x4;
        float ein_2 = agg[(size_t)i*5+0] * inv;
        float ein_3 = agg[(size_t)i*5+1] * inv;
        float ein_4 = agg[(size_t)i*5+2] * inv;
        float ein_5 = agg[(size_t)i*5+3] * inv;
        float ein_6 = agg[(size_t)i*5+4] * inv;
        NODE_MLP_BODY
        dphi_out = dphi;
    }

    x4 += dphi_out;
    float u0 = x0 + fmaxf(x0, 0.0f);
    float u1 = x1 + fmaxf(x1, 0.0f);
    float u2 = x2 + fmaxf(x2, 0.0f);
    float u3 = x3 + fmaxf(x3, 0.0f);
    float u4 = x4 + fmaxf(x4, 0.0f);

    {
        float ein_0 = u0, ein_1 = u1, ein_2 = u2, ein_3 = u3, ein_4 = u4;
        DECODER_BODY
        if (valid) out[gid] = o;
    }
}

// ---------------- fallback (atomic) kernels ----------------
__global__ void init_fb(const float* __restrict__ x, float* __restrict__ xw,
                        float* __restrict__ counts, float* __restrict__ agg) {
    int i = blockIdx.x * blockDim.x + threadIdx.x;
    if (i < NN) {
#pragma unroll
        for (int j = 0; j < 5; j++) { xw[i*5+j] = x[i*5+j]; agg[i*5+j] = 0.0f; }
        counts[i] = 0.0f;
    }
}

__global__ void count_f(const int* __restrict__ dst, float* __restrict__ counts) {
    int e = blockIdx.x * blockDim.x + threadIdx.x;
    atomicAdd(&counts[dst[e]], 1.0f);
}

__global__ __launch_bounds__(256, 2)
void edge_atomic(const float* __restrict__ xw, const float* __restrict__ edge_attr,
                 const int* __restrict__ src_idx, const int* __restrict__ dst_idx,
                 const float* __restrict__ ew1, const float* __restrict__ eb1,
                 const float* __restrict__ ew2t, const float* __restrict__ eb2,
                 const float* __restrict__ ew3, const float* __restrict__ eb3,
                 float* __restrict__ agg) {
    int e = blockIdx.x * blockDim.x + threadIdx.x;
    int s = src_idx[e];
    int d = dst_idx[e];

    float xs_0=xw[s*5+0], xs_1=xw[s*5+1], xs_2=xw[s*5+2], xs_4=xw[s*5+4];
    float xd_0=xw[d*5+0], xd_1=xw[d*5+1], xd_2=xw[d*5+2], xd_4=xw[d*5+4];
    float ea_0=edge_attr[(size_t)e*5+0], ea_1=edge_attr[(size_t)e*5+1],
          ea_2=edge_attr[(size_t)e*5+2], ea_3=edge_attr[(size_t)e*5+3],
          ea_4=edge_attr[(size_t)e*5+4];

    float ein_0 = xd_0 - xs_0;
    float ein_1 = xd_1 - xs_1;
    float ein_2 = xd_2 - xs_2;
    float ein_3 = sqrtf(ein_0*ein_0 + ein_1*ein_1 + ein_2*ein_2);
    float ein_4 = ea_0, ein_5 = ea_1, ein_6 = ea_2, ein_7 = ea_3, ein_8 = ea_4;
    float ein_9 = xs_4, ein_10 = xd_4;

    EDGE_MLP_BODY

    atomicAdd(&agg[d*5+0], ea_0 + o_0);
    atomicAdd(&agg[d*5+1], ea_1 + o_1);
    atomicAdd(&agg[d*5+2], ea_2 + o_2);
    atomicAdd(&agg[d*5+3], ea_3 + o_3);
    atomicAdd(&agg[d*5+4], ea_4 + o_4);
}

__global__ __launch_bounds__(256, 2)
void node_agg(float* __restrict__ xw, float* __restrict__ agg,
              const float* __restrict__ counts,
              const float* __restrict__ nw1, const float* __restrict__ nb1,
              const float* __restrict__ nw2t, const float* __restrict__ nb2,
              const float* __restrict__ nw3, const float* __restrict__ nb3) {
    int gid = blockIdx.x * blockDim.x + threadIdx.x;
    int i = min(gid, NN - 1);
    bool valid = (gid < NN);

    float inv = 1.0f / fmaxf(counts[i], 1.0f);
    float ein_0 = xw[i*5+3];
    float ein_1 = xw[i*5+4];
    float ein_2 = agg[i*5+0] * inv;
    float ein_3 = agg[i*5+1] * inv;
    float ein_4 = agg[i*5+2] * inv;
    float ein_5 = agg[i*5+3] * inv;
    float ein_6 = agg[i*5+4] * inv;

    NODE_MLP_BODY

    if (valid) {
        float x0=xw[i*5+0], x1=xw[i*5+1], x2=xw[i*5+2], x3=xw[i*5+3], x4=xw[i*5+4];
        x4 += dphi;
        xw[i*5+0] = x0 + fmaxf(x0, 0.0f);
        xw[i*5+1] = x1 + fmaxf(x1, 0.0f);
        xw[i*5+2] = x2 + fmaxf(x2, 0.0f);
        xw[i*5+3] = x3 + fmaxf(x3, 0.0f);
        xw[i*5+4] = x4 + fmaxf(x4, 0.0f);
        agg[i*5+0]=0.f; agg[i*5+1]=0.f; agg[i*5+2]=0.f; agg[i*5+3]=0.f; agg[i*5+4]=0.f;
    }
}

__global__ __launch_bounds__(256, 2)
void decoder_kernel(const float* __restrict__ xw,
                    const float* __restrict__ dw1, const float* __restrict__ db1,
                    const float* __restrict__ dw2t, const float* __restrict__ db2,
                    const float* __restrict__ dw3t, const float* __restrict__ db3,
                    const float* __restrict__ dw4, const float* __restrict__ db4,
                    float* __restrict__ out) {
    int gid = blockIdx.x * blockDim.x + threadIdx.x;
    int i = min(gid, NN - 1);
    bool valid = (gid < NN);

    float ein_0 = xw[i*5+0], ein_1 = xw[i*5+1], ein_2 = xw[i*5+2],
          ein_3 = xw[i*5+3], ein_4 = xw[i*5+4];

    DECODER_BODY

    if (valid) out[gid] = o;
}

extern "C" void kernel_launch(void* const* d_in, const int* in_sizes, int n_in,
                              void* d_out, int out_size, void* d_ws, size_t ws_size,
                              hipStream_t stream) {
    const float* x         = (const float*)d_in[0];
    const float* edge_attr = (const float*)d_in[1];
    const float* ew1 = (const float*)d_in[2];
    const float* eb1 = (const float*)d_in[3];
    const float* ew2 = (const float*)d_in[4];
    const float* eb2 = (const float*)d_in[5];
    const float* ew3 = (const float*)d_in[6];
    const float* eb3 = (const float*)d_in[7];
    const float* nw1 = (const float*)d_in[8];
    const float* nb1 = (const float*)d_in[9];
    const float* nw2 = (const float*)d_in[10];
    const float* nb2 = (const float*)d_in[11];
    const float* nw3 = (const float*)d_in[12];
    const float* nb3 = (const float*)d_in[13];
    const float* dw1 = (const float*)d_in[14];
    const float* db1 = (const float*)d_in[15];
    const float* dw2 = (const float*)d_in[16];
    const float* db2 = (const float*)d_in[17];
    const float* dw3 = (const float*)d_in[18];
    const float* db3 = (const float*)d_in[19];
    const float* dw4 = (const float*)d_in[20];
    const float* db4 = (const float*)d_in[21];
    const int* edge_index = (const int*)d_in[22];
    const int* src = edge_index;
    const int* dst = edge_index + NE;
    float* out = (float*)d_out;

    const size_t WS1 = (size_t)10420992 * 4;             // round-15 layout
    const size_t WS2 = (size_t)(10420992 + 500000) * 4;  // + agg[NN*5]

    if (ws_size >= WS1) {
        float* xw      = (float*)d_ws;
        int*   cnt     = (int*)d_ws + 500000;
        int*   start   = (int*)d_ws + 600000;
        int*   bcur    = (int*)d_ws + 700000;
        int*   bsum    = (int*)d_ws + 800000;
        int*   boff    = (int*)d_ws + 800512;
        float* nw2t    = (float*)d_ws + 805120;
        float* dw2t    = (float*)d_ws + 809216;
        float* dw3t    = (float*)d_ws + 813312;
        int*   eidx    = (int*)d_ws + 817408;
        float* eout    = (float*)d_ws + 2417408;
        int*   ebkt    = (int*)d_ws + 2417408;   // alias: dead before edge_mfma
        unsigned short* w1tb = (unsigned short*)((int*)d_ws + 10417408);
        unsigned short* w2tb = (unsigned short*)((int*)d_ws + 10418432);
        float* w3p8    = (float*)d_ws + 10420480;
        float* agg     = (float*)d_ws + 10420992;  // tier-1 only

        transpose64<<<64, 64, 0, stream>>>(nw2, nw2t);
        transpose64<<<64, 64, 0, stream>>>(dw2, dw2t);
        transpose64<<<64, 64, 0, stream>>>(dw3, dw3t);
        prep_wb<<<1, 256, 0, stream>>>(ew1, eb1, ew2, ew3, eb2, w1tb, w2tb, w3p8);

        init_xw<<<NGB, 256, 0, stream>>>(x, xw, bsum, bcur);
        bhist_kernel<<<250, 256, 0, stream>>>(dst, bsum);
        scanb_kernel<<<1, 512, 0, stream>>>(bsum, boff);
        sort_pass1<<<250, 256, 0, stream>>>(dst, boff, bcur, ebkt);
        sort_pass2<<<NBKT, 256, 0, stream>>>(ebkt, dst, boff, bsum, eidx, cnt, start);

        if (ws_size >= WS2) {
            // tier 1: split gather (high TLP) + dense-read MLP kernels
            edge_mfma<<<NE/256, 256, 0, stream>>>(xw, edge_attr, src, dst,
                                                  w1tb, w2tb, w3p8, eb3, eout);
            gather4<<<(NN*4 + 255)/256, 256, 0, stream>>>(eout, eidx, cnt, start, agg);
            nodeA<<<NGB, 256, 0, stream>>>(xw, agg, cnt,
                                           nw1, nb1, nw2t, nb2, nw3, nb3);
            edge_mfma<<<NE/256, 256, 0, stream>>>(xw, edge_attr, src, dst,
                                                  w1tb, w2tb, w3p8, eb3, eout);
            gather4<<<(NN*4 + 255)/256, 256, 0, stream>>>(eout, eidx, cnt, start, agg);
            nodeB<<<NGB, 256, 0, stream>>>(xw, agg, cnt,
                                           nw1, nb1, nw2t, nb2, nw3, nb3,
                                           dw1, db1, dw2t, db2, dw3t, db3, dw4, db4,
                                           out);
        } else {
            // tier 2: round-15 proven path
            edge_mfma<<<NE/256, 256, 0, stream>>>(xw, edge_attr, src, dst,
                                                  w1tb, w2tb, w3p8, eb3, eout);
            node_csr<<<NGB, 256, 0, stream>>>(xw, eout, eidx, cnt, start,
                                              nw1, nb1, nw2t, nb2, nw3, nb3);
            edge_mfma<<<NE/256, 256, 0, stream>>>(xw, edge_attr, src, dst,
                                                  w1tb, w2tb, w3p8, eb3, eout);
            node_dec<<<NGB, 256, 0, stream>>>(xw, eout, eidx, cnt, start,
                                              nw1, nb1, nw2t, nb2, nw3, nb3,
                                              dw1, db1, dw2t, db2, dw3t, db3, dw4, db4,
                                              out);
        }
    } else {
        float* xw     = (float*)d_ws;
        float* counts = (float*)d_ws + 500000;
        float* agg    = (float*)d_ws + 600000;
        float* ew2t   = (float*)d_ws + 1100000;
        float* nw2t   = (float*)d_ws + 1104096;
        float* dw2t   = (float*)d_ws + 1108192;
        float* dw3t   = (float*)d_ws + 1112288;

        transpose64<<<64, 64, 0, stream>>>(ew2, ew2t);
        transpose64<<<64, 64, 0, stream>>>(nw2, nw2t);
        transpose64<<<64, 64, 0, stream>>>(dw2, dw2t);
        transpose64<<<64, 64, 0, stream>>>(dw3, dw3t);

        init_fb<<<NGB, 256, 0, stream>>>(x, xw, counts, agg);
        count_f<<<NE/256, 256, 0, stream>>>(dst, counts);

        for (int it = 0; it < 2; it++) {
            edge_atomic<<<NE/256, 256, 0, stream>>>(xw, edge_attr, src, dst,
                                                    ew1, eb1, ew2t, eb2, ew3, eb3, agg);
            node_agg<<<NGB, 256, 0, stream>>>(xw, agg, counts,
                                              nw1, nb1, nw2t, nb2, nw3, nb3);
        }
        decoder_kernel<<<NGB, 256, 0, stream>>>(xw, dw1, db1, dw2t, db2,
                                                dw3t, db3, dw4, db4, out);
    }
}

// Round 20
// 318.092 us; speedup vs baseline: 1.7248x; 1.3875x over previous
//
#include <hip/hip_runtime.h>
#include <math.h>

#define NN 100000
#define NE 1600000
#define NGB 391
#define NBKT 391

typedef __attribute__((ext_vector_type(8))) __bf16 bf16x8;
typedef __attribute__((ext_vector_type(4))) float f32x4;
union FR { unsigned u[4]; bf16x8 v; };

__device__ __forceinline__ f32x4 MFMA(bf16x8 a, bf16x8 b, f32x4 c) {
    return __builtin_amdgcn_mfma_f32_16x16x32_bf16(a, b, c, 0, 0, 0);
}
__device__ __forceinline__ unsigned pk2(float lo, float hi) {
    union { __bf16 b[2]; unsigned u; } P;
    P.b[0] = (__bf16)lo; P.b[1] = (__bf16)hi;
    return P.u;
}
#define RELU0(v) fmaxf((v), 0.0f)

// ---------------- repetition macros (VALU fallback paths) ----------------
#define R5(M,A)  M(0,A) M(1,A) M(2,A) M(3,A) M(4,A)
#define R7(M,A)  M(0,A) M(1,A) M(2,A) M(3,A) M(4,A) M(5,A) M(6,A)
#define R11(M,A) R7(M,A) M(7,A) M(8,A) M(9,A) M(10,A)
#define R16(M,A) M(0,A) M(1,A) M(2,A) M(3,A) M(4,A) M(5,A) M(6,A) M(7,A) \
                 M(8,A) M(9,A) M(10,A) M(11,A) M(12,A) M(13,A) M(14,A) M(15,A)
#define R16I(M,A) M(0,A) M(1,A) M(2,A) M(3,A) M(4,A) M(5,A) M(6,A) M(7,A) \
                  M(8,A) M(9,A) M(10,A) M(11,A) M(12,A) M(13,A) M(14,A) M(15,A)
#define R64(M,A) \
  M(0,A) M(1,A) M(2,A) M(3,A) M(4,A) M(5,A) M(6,A) M(7,A) \
  M(8,A) M(9,A) M(10,A) M(11,A) M(12,A) M(13,A) M(14,A) M(15,A) \
  M(16,A) M(17,A) M(18,A) M(19,A) M(20,A) M(21,A) M(22,A) M(23,A) \
  M(24,A) M(25,A) M(26,A) M(27,A) M(28,A) M(29,A) M(30,A) M(31,A) \
  M(32,A) M(33,A) M(34,A) M(35,A) M(36,A) M(37,A) M(38,A) M(39,A) \
  M(40,A) M(41,A) M(42,A) M(43,A) M(44,A) M(45,A) M(46,A) M(47,A) \
  M(48,A) M(49,A) M(50,A) M(51,A) M(52,A) M(53,A) M(54,A) M(55,A) \
  M(56,A) M(57,A) M(58,A) M(59,A) M(60,A) M(61,A) M(62,A) M(63,A)

#define DECL_H1(J,P) float h1_##J = (P)[J];
#define FMA_L1(J,K)  h1_##J = fmaf(ein_##K, wrow[J], h1_##J);
#define ROW_L1(K,W)  { const float* wrow = (W) + (K)*64; R64(FMA_L1,K) }
#define RELU_H1(J,A) h1_##J = fmaxf(h1_##J, 0.0f);
#define DECL_A(K,P)  float a_##K = (P)[K];
#define FMA_L2(Q,K)  a_##K = fmaf(h1_##Q, w2p[(K)*64+Q], a_##K);
#define ROW_L2(K,A)  R64(FMA_L2,K)
#define FOLD_E(K,A) { float r = fmaxf(a_##K, 0.0f); \
  o_0 = fmaf(r, w3p[(K)*5+0], o_0); o_1 = fmaf(r, w3p[(K)*5+1], o_1); \
  o_2 = fmaf(r, w3p[(K)*5+2], o_2); o_3 = fmaf(r, w3p[(K)*5+3], o_3); \
  o_4 = fmaf(r, w3p[(K)*5+4], o_4); }
#define FOLD_N(K,A)  dphi = fmaf(fmaxf(a_##K, 0.0f), w3p[K], dphi);
#define DECL_H2(K,G) float h2##G##_##K;
#define ASG_H2(K,G)  h2##G##_##K = fmaxf(a_##K, 0.0f);
#define L2BLK(G,B)   { const float* w2p = dw2t + (B)*1024; const float* b2p = db2 + (B)*16; \
                       R16(DECL_A,b2p) R16(ROW_L2,0) R16(ASG_H2,G) }
#define FMA_L3A(Q,K) a_##K = fmaf(h2A_##Q, w3p[(K)*64+Q],    a_##K);
#define FMA_L3B(Q,K) a_##K = fmaf(h2B_##Q, w3p[(K)*64+16+Q], a_##K);
#define FMA_L3C(Q,K) a_##K = fmaf(h2C_##Q, w3p[(K)*64+32+Q], a_##K);
#define FMA_L3D(Q,K) a_##K = fmaf(h2D_##Q, w3p[(K)*64+48+Q], a_##K);
#define ROW_L3(K,A)  R16I(FMA_L3A,K) R16I(FMA_L3B,K) R16I(FMA_L3C,K) R16I(FMA_L3D,K)
#define FOLD_D(K,A)  o = fmaf(fmaxf(a_##K, 0.0f), w4p[K], o);

#define EDGE_MLP_BODY \
    R64(DECL_H1, eb1) \
    R11(ROW_L1, ew1) \
    R64(RELU_H1, 0) \
    float o_0=eb3[0], o_1=eb3[1], o_2=eb3[2], o_3=eb3[3], o_4=eb3[4]; \
    for (int kb = 0; kb < 4; kb++) { \
        const float* w2p = ew2t + kb * 1024; \
        const float* b2p = eb2 + kb * 16; \
        const float* w3p = ew3 + kb * 80; \
        R16(DECL_A, b2p) \
        R16(ROW_L2, 0) \
        R16(FOLD_E, 0) \
    }

#define NODE_MLP_BODY \
    R64(DECL_H1, nb1) \
    R7(ROW_L1, nw1) \
    R64(RELU_H1, 0) \
    float dphi = nb3[0]; \
    for (int kb = 0; kb < 4; kb++) { \
        const float* w2p = nw2t + kb * 1024; \
        const float* b2p = nb2 + kb * 16; \
        const float* w3p = nw3 + kb * 16; \
        R16(DECL_A, b2p) \
        R16(ROW_L2, 0) \
        R16(FOLD_N, 0) \
    }

#define DECODER_BODY \
    R64(DECL_H1, db1) \
    R5(ROW_L1, dw1) \
    R64(RELU_H1, 0) \
    R16(DECL_H2, A) R16(DECL_H2, B) R16(DECL_H2, C) R16(DECL_H2, D) \
    L2BLK(A, 0) L2BLK(B, 1) L2BLK(C, 2) L2BLK(D, 3) \
    float o = db4[0]; \
    for (int jb = 0; jb < 4; jb++) { \
        const float* w3p = dw3t + jb*1024; \
        const float* b3p = db3 + jb*16; \
        const float* w4p = dw4 + jb*16; \
        R16(DECL_A, b3p) \
        R16(ROW_L3, 0) \
        R16(FOLD_D, 0) \
    }

// ---------------- small utility kernels ----------------
__global__ void transpose64(const float* __restrict__ in, float* __restrict__ out) {
    int j = blockIdx.x, k = threadIdx.x;
    out[j * 64 + k] = in[k * 64 + j];
}

__global__ void prep_wb(const float* __restrict__ ew1, const float* __restrict__ eb1,
                        const float* __restrict__ ew2,
                        const float* __restrict__ ew3, const float* __restrict__ eb2,
                        unsigned short* __restrict__ w1t, unsigned short* __restrict__ w2t,
                        float* __restrict__ w3p) {
    int t = threadIdx.x;
    for (int idx = t; idx < 64*32; idx += 256) {
        int m = idx >> 5, k = idx & 31;
        float v = (k < 11) ? ew1[k*64 + m] : (k == 11 ? eb1[m] : 0.0f);
        union { __bf16 b; unsigned short u; } U; U.b = (__bf16)v;
        w1t[idx] = U.u;
    }
    for (int idx = t; idx < 64*64; idx += 256) {
        int m = idx >> 6, k = idx & 63;
        union { __bf16 b; unsigned short u; } U; U.b = (__bf16)(ew2[k*64 + m]);
        w2t[idx] = U.u;
    }
    for (int idx = t; idx < 64*8; idx += 256) {
        int F = idx >> 3, j = idx & 7;
        w3p[idx] = (j < 5) ? ew3[F*5 + j] : (j == 5 ? eb2[F] : 0.0f);
    }
}

// bf16/padded NODE+DECODER weights for MFMA node kernels
__global__ void prep_nd(const float* __restrict__ nw1, const float* __restrict__ nb1,
                        const float* __restrict__ nw2, const float* __restrict__ nw3,
                        const float* __restrict__ nb2,
                        const float* __restrict__ dw1, const float* __restrict__ db1,
                        const float* __restrict__ dw2, const float* __restrict__ dw3,
                        const float* __restrict__ dw4, const float* __restrict__ db3,
                        unsigned short* __restrict__ w1n, unsigned short* __restrict__ w2n,
                        float* __restrict__ w3pn,
                        unsigned short* __restrict__ d1t, unsigned short* __restrict__ d2t,
                        unsigned short* __restrict__ d3t, float* __restrict__ w4pd) {
    int t = threadIdx.x;
    union { __bf16 b; unsigned short u; } U;
    for (int idx = t; idx < 2048; idx += 256) {
        int m = idx >> 5, k = idx & 31;
        float v = (k < 7) ? nw1[k*64 + m] : (k == 7 ? nb1[m] : 0.0f);
        U.b = (__bf16)v; w1n[idx] = U.u;
    }
    for (int idx = t; idx < 4096; idx += 256) {
        int m = idx >> 6, k = idx & 63;
        U.b = (__bf16)(nw2[k*64 + m]); w2n[idx] = U.u;
    }
    for (int idx = t; idx < 128; idx += 256) {
        int F = idx >> 1;
        w3pn[idx] = (idx & 1) ? nb2[F] : nw3[F];
    }
    for (int idx = t; idx < 2048; idx += 256) {
        int m = idx >> 5, k = idx & 31;
        float v = (k < 5) ? dw1[k*64 + m] : (k == 5 ? db1[m] : 0.0f);
        U.b = (__bf16)v; d1t[idx] = U.u;
    }
    for (int idx = t; idx < 4096; idx += 256) {
        int m = idx >> 6, k = idx & 63;
        U.b = (__bf16)(dw2[k*64 + m]); d2t[idx] = U.u;
    }
    for (int idx = t; idx < 4096; idx += 256) {
        int m = idx >> 6, k = idx & 63;
        U.b = (__bf16)(dw3[k*64 + m]); d3t[idx] = U.u;
    }
    for (int idx = t; idx < 128; idx += 256) {
        int F = idx >> 1;
        w4pd[idx] = (idx & 1) ? db3[F] : dw4[F];
    }
}

__global__ void init_xw(const float* __restrict__ x, float* __restrict__ xw,
                        int* __restrict__ bsum, int* __restrict__ bcur) {
    int i = blockIdx.x * blockDim.x + threadIdx.x;
    if (i < NN) {
#pragma unroll
        for (int j = 0; j < 5; j++) xw[i*5+j] = x[i*5+j];
    }
    if (i < 512) bsum[i] = 0;
    if (i < NBKT) bcur[i] = 0;
}

__global__ __launch_bounds__(256)
void bhist_kernel(const int* __restrict__ dst, int* __restrict__ bsum) {
    __shared__ int h[NBKT];
    int t = threadIdx.x;
    for (int i = t; i < NBKT; i += 256) h[i] = 0;
    __syncthreads();
    int eb = blockIdx.x * 6400;
#pragma unroll
    for (int it = 0; it < 25; ++it) {
        int e = eb + it*256 + t;
        atomicAdd(&h[dst[e] >> 8], 1);
    }
    __syncthreads();
    for (int i = t; i < NBKT; i += 256)
        if (h[i]) atomicAdd(&bsum[i], h[i]);
}

__global__ void scanb_kernel(const int* __restrict__ bsum, int* __restrict__ boff) {
    __shared__ int s[512];
    int t = threadIdx.x;
    int v0 = (t < NGB) ? bsum[t] : 0;
    s[t] = v0;
    __syncthreads();
    for (int o = 1; o < 512; o <<= 1) {
        int v = (t >= o) ? s[t - o] : 0;
        __syncthreads();
        s[t] += v;
        __syncthreads();
    }
    if (t < NGB) boff[t] = s[t] - v0;
}

__global__ __launch_bounds__(256)
void sort_pass1(const int* __restrict__ dst, const int* __restrict__ boff,
                int* __restrict__ bcur, int* __restrict__ ebkt) {
    __shared__ int hist[NBKT];
    __shared__ int s[512];
    __shared__ int scanBase[NBKT];
    __shared__ int cur[NBKT];
    __shared__ int gbase[NBKT];
    __shared__ int stage[6400];
    int t = threadIdx.x;
    int eb = blockIdx.x * 6400;

    for (int i = t; i < NBKT; i += 256) hist[i] = 0;
    __syncthreads();
#pragma unroll
    for (int it = 0; it < 25; ++it) {
        int e = eb + it*256 + t;
        atomicAdd(&hist[dst[e] >> 8], 1);
    }
    __syncthreads();
    s[t]       = (t < NBKT) ? hist[t] : 0;
    s[t + 256] = (t + 256 < NBKT) ? hist[t + 256] : 0;
    __syncthreads();
    for (int o = 1; o < 512; o <<= 1) {
        int v0 = (t >= o) ? s[t - o] : 0;
        int v1 = ((t + 256) >= o) ? s[t + 256 - o] : 0;
        __syncthreads();
        s[t] += v0; s[t + 256] += v1;
        __syncthreads();
    }
    for (int i = t; i < NBKT; i += 256) {
        int ex = s[i] - hist[i];
        scanBase[i] = ex;
        cur[i] = ex;
        gbase[i] = (hist[i] > 0) ? atomicAdd(&bcur[i], hist[i]) : 0;
    }
    __syncthreads();
#pragma unroll
    for (int it = 0; it < 25; ++it) {
        int e = eb + it*256 + t;
        int b = dst[e] >> 8;
        int ls = atomicAdd(&cur[b], 1);
        stage[ls] = (b << 21) | e;
    }
    __syncthreads();
#pragma unroll
    for (int it = 0; it < 25; ++it) {
        int k = it*256 + t;
        int p = stage[k];
        int b = p >> 21;
        int e = p & 0x1FFFFF;
        ebkt[boff[b] + gbase[b] + (k - scanBase[b])] = e;
    }
}

__global__ __launch_bounds__(256)
void sort_pass2(const int* __restrict__ ebkt, const int* __restrict__ dst,
                const int* __restrict__ boff, const int* __restrict__ bsum,
                int* __restrict__ eidx, int* __restrict__ cnt, int* __restrict__ start) {
    __shared__ int ncnt[256];
    __shared__ int s[256];
    __shared__ int lbase[256];
    __shared__ int lcur[256];
    __shared__ int outst[6144];
    int b = blockIdx.x, t = threadIdx.x;
    int node0 = b << 8;
    int nb = bsum[b];
    int base = boff[b];

    ncnt[t] = 0;
    __syncthreads();
    for (int k = t; k < nb; k += 256) {
        int e = ebkt[base + k];
        atomicAdd(&ncnt[dst[e] - node0], 1);
    }
    __syncthreads();
    int c = ncnt[t];
    s[t] = c;
    __syncthreads();
    for (int o = 1; o < 256; o <<= 1) {
        int v = (t >= o) ? s[t - o] : 0;
        __syncthreads();
        s[t] += v;
        __syncthreads();
    }
    lbase[t] = s[t] - c;
    lcur[t] = 0;
    __syncthreads();
    for (int k = t; k < nb; k += 256) {
        int e = ebkt[base + k];
        int dl = dst[e] - node0;
        int ls = lbase[dl] + atomicAdd(&lcur[dl], 1);
        outst[ls] = e;
    }
    __syncthreads();
    for (int k = t; k < nb; k += 256) eidx[base + k] = outst[k];
    int i = node0 + t;
    if (i < NN) { cnt[i] = c; start[i] = base + lbase[t]; }
}

// ---------------- MFMA edge kernel ----------------
#define EPI1(MT,RR,C2) { \
    int F = (MT)*16 + 4*g + (RR); \
    const float4* wq = reinterpret_cast<const float4*>(w3p + F*8); \
    float4 wA = wq[0]; float4 wB = wq[1]; \
    float hh = fmaxf(C2[RR] + wB.y, 0.f); \
    o0=fmaf(hh,wA.x,o0); o1=fmaf(hh,wA.y,o1); o2=fmaf(hh,wA.z,o2); \
    o3=fmaf(hh,wA.w,o3); o4=fmaf(hh,wB.x,o4); }

template<int NT>
__device__ __forceinline__ void proc_nt(
    unsigned q0, unsigned q1, unsigned q2, unsigned q3, unsigned q4, unsigned q5,
    FR a1_0, FR a1_1, FR a1_2, FR a1_3,
    FR a2_00, FR a2_01, FR a2_10, FR a2_11,
    FR a2_20, FR a2_21, FR a2_30, FR a2_31,
    const float* __restrict__ w3p,
    int g, int c, int srcA, int srcB, bool hi2,
    float& s0, float& s1, float& s2, float& s3, float& s4)
{
    f32x4 z = {0.f, 0.f, 0.f, 0.f};

    int srcl = NT*16 + c;
    unsigned m0=__shfl(q0,srcl), m1=__shfl(q1,srcl), m2=__shfl(q2,srcl);
    unsigned m3=__shfl(q3,srcl), m4=__shfl(q4,srcl), m5=__shfl(q5,srcl);
    FR B;
    B.u[0] = (g==0)?m0:((g==1)?m4:0u);
    B.u[1] = (g==0)?m1:((g==1)?m5:0u);
    B.u[2] = (g==0)?m2:0u;
    B.u[3] = (g==0)?m3:0u;
    f32x4 c1_0 = MFMA(a1_0.v, B.v, z);
    f32x4 c1_1 = MFMA(a1_1.v, B.v, z);
    f32x4 c1_2 = MFMA(a1_2.v, B.v, z);
    f32x4 c1_3 = MFMA(a1_3.v, B.v, z);

    unsigned pk01_0 = pk2(RELU0(c1_0[0]), RELU0(c1_0[1]));
    unsigned pk23_0 = pk2(RELU0(c1_0[2]), RELU0(c1_0[3]));
    unsigned pk01_1 = pk2(RELU0(c1_1[0]), RELU0(c1_1[1]));
    unsigned pk23_1 = pk2(RELU0(c1_1[2]), RELU0(c1_1[3]));
    unsigned pk01_2 = pk2(RELU0(c1_2[0]), RELU0(c1_2[1]));
    unsigned pk23_2 = pk2(RELU0(c1_2[2]), RELU0(c1_2[3]));
    unsigned pk01_3 = pk2(RELU0(c1_3[0]), RELU0(c1_3[1]));
    unsigned pk23_3 = pk2(RELU0(c1_3[2]), RELU0(c1_3[3]));

    FR B20;
    {
        unsigned sA0=__shfl(pk01_0,srcA), sA1=__shfl(pk01_1,srcA);
        unsigned sB0=__shfl(pk23_0,srcA), sB1=__shfl(pk23_1,srcA);
        unsigned sC0=__shfl(pk01_0,srcB), sC1=__shfl(pk01_1,srcB);
        unsigned sD0=__shfl(pk23_0,srcB), sD1=__shfl(pk23_1,srcB);
        B20.u[0]=hi2?sA1:sA0; B20.u[1]=hi2?sB1:sB0;
        B20.u[2]=hi2?sC1:sC0; B20.u[3]=hi2?sD1:sD0;
    }
    FR B21;
    {
        unsigned sA0=__shfl(pk01_2,srcA), sA1=__shfl(pk01_3,srcA);
        unsigned sB0=__shfl(pk23_2,srcA), sB1=__shfl(pk23_3,srcA);
        unsigned sC0=__shfl(pk01_2,srcB), sC1=__shfl(pk01_3,srcB);
        unsigned sD0=__shfl(pk23_2,srcB), sD1=__shfl(pk23_3,srcB);
        B21.u[0]=hi2?sA1:sA0; B21.u[1]=hi2?sB1:sB0;
        B21.u[2]=hi2?sC1:sC0; B21.u[3]=hi2?sD1:sD0;
    }
    f32x4 c2_0 = MFMA(a2_00.v, B20.v, z);   c2_0 = MFMA(a2_01.v, B21.v, c2_0);
    f32x4 c2_1 = MFMA(a2_10.v, B20.v, z);   c2_1 = MFMA(a2_11.v, B21.v, c2_1);
    f32x4 c2_2 = MFMA(a2_20.v, B20.v, z);   c2_2 = MFMA(a2_21.v, B21.v, c2_2);
    f32x4 c2_3 = MFMA(a2_30.v, B20.v, z);   c2_3 = MFMA(a2_31.v, B21.v, c2_3);

    float o0=0.f, o1=0.f, o2=0.f, o3=0.f, o4=0.f;
    EPI1(0,0,c2_0) EPI1(0,1,c2_0) EPI1(0,2,c2_0) EPI1(0,3,c2_0)
    EPI1(1,0,c2_1) EPI1(1,1,c2_1) EPI1(1,2,c2_1) EPI1(1,3,c2_1)
    EPI1(2,0,c2_2) EPI1(2,1,c2_2) EPI1(2,2,c2_2) EPI1(2,3,c2_2)
    EPI1(3,0,c2_3) EPI1(3,1,c2_3) EPI1(3,2,c2_3) EPI1(3,3,c2_3)

    o0 += __shfl_xor(o0,16); o0 += __shfl_xor(o0,32);
    o1 += __shfl_xor(o1,16); o1 += __shfl_xor(o1,32);
    o2 += __shfl_xor(o2,16); o2 += __shfl_xor(o2,32);
    o3 += __shfl_xor(o3,16); o3 += __shfl_xor(o3,32);
    o4 += __shfl_xor(o4,16); o4 += __shfl_xor(o4,32);

    if (g == NT) { s0 = o0; s1 = o1; s2 = o2; s3 = o3; s4 = o4; }
}

#define LOAD_A1(MT) FR a1_##MT; \
    *reinterpret_cast<uint4*>(a1_##MT.u) = \
        *reinterpret_cast<const uint4*>(w1t + ((MT)*16 + c)*32 + 8*g);
#define LOAD_A2(MT) FR a2_##MT##_0, a2_##MT##_1; \
    *reinterpret_cast<uint4*>(a2_##MT##_0.u) = \
        *reinterpret_cast<const uint4*>(w2t + ((MT)*16 + c)*64 + 8*g); \
    *reinterpret_cast<uint4*>(a2_##MT##_1.u) = \
        *reinterpret_cast<const uint4*>(w2t + ((MT)*16 + c)*64 + 32 + 8*g);

__global__ __launch_bounds__(256, 4)
void edge_mfma(const float* __restrict__ xw, const float* __restrict__ edge_attr,
               const int* __restrict__ src_idx, const int* __restrict__ dst_idx,
               const unsigned short* __restrict__ w1t, const unsigned short* __restrict__ w2t,
               const float* __restrict__ w3p, const float* __restrict__ eb3,
               float* __restrict__ eout) {
    int tid = threadIdx.x;
    int l = tid & 63;
    int g = l >> 4;
    int c = l & 15;
    int e = blockIdx.x * 256 + tid;

    int s = src_idx[e];
    int d = dst_idx[e];
    float xs_0=xw[s*5+0], xs_1=xw[s*5+1], xs_2=xw[s*5+2], xs_4=xw[s*5+4];
    float xd_0=xw[d*5+0], xd_1=xw[d*5+1], xd_2=xw[d*5+2], xd_4=xw[d*5+4];
    float ea_0=edge_attr[(size_t)e*5+0], ea_1=edge_attr[(size_t)e*5+1],
          ea_2=edge_attr[(size_t)e*5+2], ea_3=edge_attr[(size_t)e*5+3],
          ea_4=edge_attr[(size_t)e*5+4];

    float ein_0 = xd_0 - xs_0;
    float ein_1 = xd_1 - xs_1;
    float ein_2 = xd_2 - xs_2;
    float ein_3 = sqrtf(ein_0*ein_0 + ein_1*ein_1 + ein_2*ein_2);

    unsigned q0 = pk2(ein_0, ein_1);
    unsigned q1 = pk2(ein_2, ein_3);
    unsigned q2 = pk2(ea_0, ea_1);
    unsigned q3 = pk2(ea_2, ea_3);
    unsigned q4 = pk2(ea_4, xs_4);
    unsigned q5 = pk2(xd_4, 1.0f);

    LOAD_A1(0) LOAD_A1(1) LOAD_A1(2) LOAD_A1(3)
    LOAD_A2(0) LOAD_A2(1) LOAD_A2(2) LOAD_A2(3)

    int srcA = (g & 1) * 32 + c;
    int srcB = srcA + 16;
    bool hi2 = (g & 2) != 0;

    float s0 = 0.f, s1 = 0.f, s2 = 0.f, s3 = 0.f, s4 = 0.f;
    proc_nt<0>(q0,q1,q2,q3,q4,q5, a1_0,a1_1,a1_2,a1_3,
               a2_0_0,a2_0_1,a2_1_0,a2_1_1,a2_2_0,a2_2_1,a2_3_0,a2_3_1,
               w3p, g, c, srcA, srcB, hi2, s0,s1,s2,s3,s4);
    proc_nt<1>(q0,q1,q2,q3,q4,q5, a1_0,a1_1,a1_2,a1_3,
               a2_0_0,a2_0_1,a2_1_0,a2_1_1,a2_2_0,a2_2_1,a2_3_0,a2_3_1,
               w3p, g, c, srcA, srcB, hi2, s0,s1,s2,s3,s4);
    proc_nt<2>(q0,q1,q2,q3,q4,q5, a1_0,a1_1,a1_2,a1_3,
               a2_0_0,a2_0_1,a2_1_0,a2_1_1,a2_2_0,a2_2_1,a2_3_0,a2_3_1,
               w3p, g, c, srcA, srcB, hi2, s0,s1,s2,s3,s4);
    proc_nt<3>(q0,q1,q2,q3,q4,q5, a1_0,a1_1,a1_2,a1_3,
               a2_0_0,a2_0_1,a2_1_0,a2_1_1,a2_2_0,a2_2_1,a2_3_0,a2_3_1,
               w3p, g, c, srcA, srcB, hi2, s0,s1,s2,s3,s4);

    float b30 = eb3[0], b31 = eb3[1], b32 = eb3[2], b33 = eb3[3], b34 = eb3[4];
    float* row = eout + (size_t)e * 5;
    row[0] = ea_0 + b30 + s0;
    row[1] = ea_1 + b31 + s1;
    row[2] = ea_2 + b32 + s2;
    row[3] = ea_3 + b33 + s3;
    row[4] = ea_4 + b34 + s4;
}

// ---------------- gather (tier-1) ----------------
__global__ __launch_bounds__(256)
void gather4(const float* __restrict__ eout, const int* __restrict__ eidx,
             const int* __restrict__ cnt, const int* __restrict__ start,
             float* __restrict__ agg) {
    int gid = blockIdx.x * 256 + threadIdx.x;
    int node = gid >> 2;
    int sub = gid & 3;
    int i = min(node, NN - 1);
    int nE = cnt[i];
    int base = start[i];
    float g0=0.f, g1=0.f, g2=0.f, g3=0.f, g4=0.f;
    for (int j = sub; j < nE; j += 4) {
        int e0 = eidx[base + j];
        const float* p = eout + (size_t)e0 * 5;
        g0 += p[0]; g1 += p[1]; g2 += p[2]; g3 += p[3]; g4 += p[4];
    }
    g0 += __shfl_xor(g0, 1); g0 += __shfl_xor(g0, 2);
    g1 += __shfl_xor(g1, 1); g1 += __shfl_xor(g1, 2);
    g2 += __shfl_xor(g2, 1); g2 += __shfl_xor(g2, 2);
    g3 += __shfl_xor(g3, 1); g3 += __shfl_xor(g3, 2);
    g4 += __shfl_xor(g4, 1); g4 += __shfl_xor(g4, 2);
    if (sub == 0 && node < NN) {
        agg[(size_t)node*5+0] = g0;
        agg[(size_t)node*5+1] = g1;
        agg[(size_t)node*5+2] = g2;
        agg[(size_t)node*5+3] = g3;
        agg[(size_t)node*5+4] = g4;
    }
}

// ---------------- MFMA node kernels (tier-1) ----------------
#define LDW32(A_, PTR, MT) *reinterpret_cast<uint4*>(A_.u) = \
    *reinterpret_cast<const uint4*>((PTR) + ((MT)*16 + c)*32 + 8*g);
#define LDW64(A0_, A1_, PTR, MT) \
    *reinterpret_cast<uint4*>(A0_.u) = *reinterpret_cast<const uint4*>((PTR) + ((MT)*16 + c)*64 + 8*g); \
    *reinterpret_cast<uint4*>(A1_.u) = *reinterpret_cast<const uint4*>((PTR) + ((MT)*16 + c)*64 + 32 + 8*g);

// node MLP for tile NT; inputs q0..q3 (k=0..7), weights w1n/w2n/w3pn; result -> sN
#define NODE_NT(NT) { \
    int srcl = (NT)*16 + c; \
    unsigned m0=__shfl(q0,srcl), m1=__shfl(q1,srcl), m2=__shfl(q2,srcl), m3=__shfl(q3,srcl); \
    FR B; B.u[0]=(g==0)?m0:0u; B.u[1]=(g==0)?m1:0u; B.u[2]=(g==0)?m2:0u; B.u[3]=(g==0)?m3:0u; \
    FR A0, A1; f32x4 z = {0.f,0.f,0.f,0.f}; \
    LDW32(A0, w1n, 0) f32x4 c1_0 = MFMA(A0.v, B.v, z); \
    LDW32(A0, w1n, 1) f32x4 c1_1 = MFMA(A0.v, B.v, z); \
    LDW32(A0, w1n, 2) f32x4 c1_2 = MFMA(A0.v, B.v, z); \
    LDW32(A0, w1n, 3) f32x4 c1_3 = MFMA(A0.v, B.v, z); \
    unsigned pk01_0=pk2(RELU0(c1_0[0]),RELU0(c1_0[1])), pk23_0=pk2(RELU0(c1_0[2]),RELU0(c1_0[3])); \
    unsigned pk01_1=pk2(RELU0(c1_1[0]),RELU0(c1_1[1])), pk23_1=pk2(RELU0(c1_1[2]),RELU0(c1_1[3])); \
    unsigned pk01_2=pk2(RELU0(c1_2[0]),RELU0(c1_2[1])), pk23_2=pk2(RELU0(c1_2[2]),RELU0(c1_2[3])); \
    unsigned pk01_3=pk2(RELU0(c1_3[0]),RELU0(c1_3[1])), pk23_3=pk2(RELU0(c1_3[2]),RELU0(c1_3[3])); \
    FR B20, B21; \
    { unsigned sA0=__shfl(pk01_0,srcA), sA1=__shfl(pk01_1,srcA); \
      unsigned sB0=__shfl(pk23_0,srcA), sB1=__shfl(pk23_1,srcA); \
      unsigned sC0=__shfl(pk01_0,srcB), sC1=__shfl(pk01_1,srcB); \
      unsigned sD0=__shfl(pk23_0,srcB), sD1=__shfl(pk23_1,srcB); \
      B20.u[0]=hi2?sA1:sA0; B20.u[1]=hi2?sB1:sB0; B20.u[2]=hi2?sC1:sC0; B20.u[3]=hi2?sD1:sD0; } \
    { unsigned sA0=__shfl(pk01_2,srcA), sA1=__shfl(pk01_3,srcA); \
      unsigned sB0=__shfl(pk23_2,srcA), sB1=__shfl(pk23_3,srcA); \
      unsigned sC0=__shfl(pk01_2,srcB), sC1=__shfl(pk01_3,srcB); \
      unsigned sD0=__shfl(pk23_2,srcB), sD1=__shfl(pk23_3,srcB); \
      B21.u[0]=hi2?sA1:sA0; B21.u[1]=hi2?sB1:sB0; B21.u[2]=hi2?sC1:sC0; B21.u[3]=hi2?sD1:sD0; } \
    float oN = 0.f; \
    { LDW64(A0, A1, w2n, 0) f32x4 c2 = MFMA(A0.v,B20.v,z); c2 = MFMA(A1.v,B21.v,c2); \
      const float4* wp = reinterpret_cast<const float4*>(w3pn + (0*16 + 4*g)*2); \
      float4 wa = wp[0], wb = wp[1]; \
      oN = fmaf(RELU0(c2[0]+wa.y), wa.x, oN); oN = fmaf(RELU0(c2[1]+wa.w), wa.z, oN); \
      oN = fmaf(RELU0(c2[2]+wb.y), wb.x, oN); oN = fmaf(RELU0(c2[3]+wb.w), wb.z, oN); } \
    { LDW64(A0, A1, w2n, 1) f32x4 c2 = MFMA(A0.v,B20.v,z); c2 = MFMA(A1.v,B21.v,c2); \
      const float4* wp = reinterpret_cast<const float4*>(w3pn + (1*16 + 4*g)*2); \
      float4 wa = wp[0], wb = wp[1]; \
      oN = fmaf(RELU0(c2[0]+wa.y), wa.x, oN); oN = fmaf(RELU0(c2[1]+wa.w), wa.z, oN); \
      oN = fmaf(RELU0(c2[2]+wb.y), wb.x, oN); oN = fmaf(RELU0(c2[3]+wb.w), wb.z, oN); } \
    { LDW64(A0, A1, w2n, 2) f32x4 c2 = MFMA(A0.v,B20.v,z); c2 = MFMA(A1.v,B21.v,c2); \
      const float4* wp = reinterpret_cast<const float4*>(w3pn + (2*16 + 4*g)*2); \
      float4 wa = wp[0], wb = wp[1]; \
      oN = fmaf(RELU0(c2[0]+wa.y), wa.x, oN); oN = fmaf(RELU0(c2[1]+wa.w), wa.z, oN); \
      oN = fmaf(RELU0(c2[2]+wb.y), wb.x, oN); oN = fmaf(RELU0(c2[3]+wb.w), wb.z, oN); } \
    { LDW64(A0, A1, w2n, 3) f32x4 c2 = MFMA(A0.v,B20.v,z); c2 = MFMA(A1.v,B21.v,c2); \
      const float4* wp = reinterpret_cast<const float4*>(w3pn + (3*16 + 4*g)*2); \
      float4 wa = wp[0], wb = wp[1]; \
      oN = fmaf(RELU0(c2[0]+wa.y), wa.x, oN); oN = fmaf(RELU0(c2[1]+wa.w), wa.z, oN); \
      oN = fmaf(RELU0(c2[2]+wb.y), wb.x, oN); oN = fmaf(RELU0(c2[3]+wb.w), wb.z, oN); } \
    oN += __shfl_xor(oN,16); oN += __shfl_xor(oN,32); \
    if (g == (NT)) sN = oN; \
}

// decoder for tile NT; inputs qd0..qd2; weights d1t/d2t/d3t/db2/w4pd; result -> sD
#define DEC_L3MT(MT) { \
    LDW64(A0, A1, d3t, MT) f32x4 c3 = MFMA(A0.v,B20e.v,z); c3 = MFMA(A1.v,B21e.v,c3); \
    const float4* wp = reinterpret_cast<const float4*>(w4pd + ((MT)*16 + 4*g)*2); \
    float4 wa = wp[0], wb = wp[1]; \
    oD = fmaf(RELU0(c3[0]+wa.y), wa.x, oD); oD = fmaf(RELU0(c3[1]+wa.w), wa.z, oD); \
    oD = fmaf(RELU0(c3[2]+wb.y), wb.x, oD); oD = fmaf(RELU0(c3[3]+wb.w), wb.z, oD); }

#define DEC_NT(NT) { \
    int srcl = (NT)*16 + c; \
    unsigned m0=__shfl(qd0,srcl), m1=__shfl(qd1,srcl), m2=__shfl(qd2,srcl); \
    FR B; B.u[0]=(g==0)?m0:0u; B.u[1]=(g==0)?m1:0u; B.u[2]=(g==0)?m2:0u; B.u[3]=0u; \
    FR A0, A1; f32x4 z = {0.f,0.f,0.f,0.f}; \
    LDW32(A0, d1t, 0) f32x4 c1_0 = MFMA(A0.v, B.v, z); \
    LDW32(A0, d1t, 1) f32x4 c1_1 = MFMA(A0.v, B.v, z); \
    LDW32(A0, d1t, 2) f32x4 c1_2 = MFMA(A0.v, B.v, z); \
    LDW32(A0, d1t, 3) f32x4 c1_3 = MFMA(A0.v, B.v, z); \
    unsigned pk01_0=pk2(RELU0(c1_0[0]),RELU0(c1_0[1])), pk23_0=pk2(RELU0(c1_0[2]),RELU0(c1_0[3])); \
    unsigned pk01_1=pk2(RELU0(c1_1[0]),RELU0(c1_1[1])), pk23_1=pk2(RELU0(c1_1[2]),RELU0(c1_1[3])); \
    unsigned pk01_2=pk2(RELU0(c1_2[0]),RELU0(c1_2[1])), pk23_2=pk2(RELU0(c1_2[2]),RELU0(c1_2[3])); \
    unsigned pk01_3=pk2(RELU0(c1_3[0]),RELU0(c1_3[1])), pk23_3=pk2(RELU0(c1_3[2]),RELU0(c1_3[3])); \
    FR B20, B21; \
    { unsigned sA0=__shfl(pk01_0,srcA), sA1=__shfl(pk01_1,srcA); \
      unsigned sB0=__shfl(pk23_0,srcA), sB1=__shfl(pk23_1,srcA); \
      unsigned sC0=__shfl(pk01_0,srcB), sC1=__shfl(pk01_1,srcB); \
      unsigned sD0=__shfl(pk23_0,srcB), sD1=__shfl(pk23_1,srcB); \
      B20.u[0]=hi2?sA1:sA0; B20.u[1]=hi2?sB1:sB0; B20.u[2]=hi2?sC1:sC0; B20.u[3]=hi2?sD1:sD0; } \
    { unsigned sA0=__shfl(pk01_2,srcA), sA1=__shfl(pk01_3,srcA); \
      unsigned sB0=__shfl(pk23_2,srcA), sB1=__shfl(pk23_3,srcA); \
      unsigned sC0=__shfl(pk01_2,srcB), sC1=__shfl(pk01_3,srcB); \
      unsigned sD0=__shfl(pk23_2,srcB), sD1=__shfl(pk23_3,srcB); \
      B21.u[0]=hi2?sA1:sA0; B21.u[1]=hi2?sB1:sB0; B21.u[2]=hi2?sC1:sC0; B21.u[3]=hi2?sD1:sD0; } \
    unsigned npk01_0, npk23_0, npk01_1, npk23_1, npk01_2, npk23_2, npk01_3, npk23_3; \
    { LDW64(A0, A1, d2t, 0) f32x4 c2 = MFMA(A0.v,B20.v,z); c2 = MFMA(A1.v,B21.v,c2); \
      float4 bb = *reinterpret_cast<const float4*>(db2 + 0*16 + 4*g); \
      npk01_0 = pk2(RELU0(c2[0]+bb.x), RELU0(c2[1]+bb.y)); \
      npk23_0 = pk2(RELU0(c2[2]+bb.z), RELU0(c2[3]+bb.w)); } \
    { LDW64(A0, A1, d2t, 1) f32x4 c2 = MFMA(A0.v,B20.v,z); c2 = MFMA(A1.v,B21.v,c2); \
      float4 bb = *reinterpret_cast<const float4*>(db2 + 1*16 + 4*g); \
      npk01_1 = pk2(RELU0(c2[0]+bb.x), RELU0(c2[1]+bb.y)); \
      npk23_1 = pk2(RELU0(c2[2]+bb.z), RELU0(c2[3]+bb.w)); } \
    { LDW64(A0, A1, d2t, 2) f32x4 c2 = MFMA(A0.v,B20.v,z); c2 = MFMA(A1.v,B21.v,c2); \
      float4 bb = *reinterpret_cast<const float4*>(db2 + 2*16 + 4*g); \
      npk01_2 = pk2(RELU0(c2[0]+bb.x), RELU0(c2[1]+bb.y)); \
      npk23_2 = pk2(RELU0(c2[2]+bb.z), RELU0(c2[3]+bb.w)); } \
    { LDW64(A0, A1, d2t, 3) f32x4 c2 = MFMA(A0.v,B20.v,z); c2 = MFMA(A1.v,B21.v,c2); \
      float4 bb = *reinterpret_cast<const float4*>(db2 + 3*16 + 4*g); \
      npk01_3 = pk2(RELU0(c2[0]+bb.x), RELU0(c2[1]+bb.y)); \
      npk23_3 = pk2(RELU0(c2[2]+bb.z), RELU0(c2[3]+bb.w)); } \
    FR B20e, B21e; \
    { unsigned sA0=__shfl(npk01_0,srcA), sA1=__shfl(npk01_1,srcA); \
      unsigned sB0=__shfl(npk23_0,srcA), sB1=__shfl(npk23_1,srcA); \
      unsigned sC0=__shfl(npk01_0,srcB), sC1=__shfl(npk01_1,srcB); \
      unsigned sD0=__shfl(npk23_0,srcB), sD1=__shfl(npk23_1,srcB); \
      B20e.u[0]=hi2?sA1:sA0; B20e.u[1]=hi2?sB1:sB0; B20e.u[2]=hi2?sC1:sC0; B20e.u[3]=hi2?sD1:sD0; } \
    { unsigned sA0=__shfl(npk01_2,srcA), sA1=__shfl(npk01_3,srcA); \
      unsigned sB0=__shfl(npk23_2,srcA), sB1=__shfl(npk23_3,srcA); \
      unsigned sC0=__shfl(npk01_2,srcB), sC1=__shfl(npk01_3,srcB); \
      unsigned sD0=__shfl(npk23_2,srcB), sD1=__shfl(npk23_3,srcB); \
      B21e.u[0]=hi2?sA1:sA0; B21e.u[1]=hi2?sB1:sB0; B21e.u[2]=hi2?sC1:sC0; B21e.u[3]=hi2?sD1:sD0; } \
    float oD = 0.f; \
    DEC_L3MT(0) DEC_L3MT(1) DEC_L3MT(2) DEC_L3MT(3) \
    oD += __shfl_xor(oD,16); oD += __shfl_xor(oD,32); \
    if (g == (NT)) sD = oD; \
}

__global__ __launch_bounds__(256, 4)
void node_mfma(float* __restrict__ xw, const float* __restrict__ agg,
               const int* __restrict__ cnt,
               const unsigned short* __restrict__ w1n, const unsigned short* __restrict__ w2n,
               const float* __restrict__ w3pn, const float* __restrict__ nb3) {
    int tid = threadIdx.x;
    int l = tid & 63;
    int g = l >> 4;
    int c = l & 15;
    int gid = blockIdx.x * 256 + tid;
    int i = min(gid, NN - 1);

    float inv = 1.0f / fmaxf((float)cnt[i], 1.0f);
    float x0=xw[i*5+0], x1=xw[i*5+1], x2=xw[i*5+2], x3=xw[i*5+3], x4=xw[i*5+4];
    float e2 = agg[(size_t)i*5+0]*inv, e3 = agg[(size_t)i*5+1]*inv, e4 = agg[(size_t)i*5+2]*inv,
          e5 = agg[(size_t)i*5+3]*inv, e6 = agg[(size_t)i*5+4]*inv;

    unsigned q0 = pk2(x3, x4);
    unsigned q1 = pk2(e2, e3);
    unsigned q2 = pk2(e4, e5);
    unsigned q3 = pk2(e6, 1.0f);

    int srcA = (g & 1) * 32 + c;
    int srcB = srcA + 16;
    bool hi2 = (g & 2) != 0;

    float sN = 0.f;
    NODE_NT(0) NODE_NT(1) NODE_NT(2) NODE_NT(3)

    float dphi = nb3[0] + sN;
    if (gid < NN) {
        x4 += dphi;
        xw[i*5+0] = x0 + fmaxf(x0, 0.0f);
        xw[i*5+1] = x1 + fmaxf(x1, 0.0f);
        xw[i*5+2] = x2 + fmaxf(x2, 0.0f);
        xw[i*5+3] = x3 + fmaxf(x3, 0.0f);
        xw[i*5+4] = x4 + fmaxf(x4, 0.0f);
    }
}

__global__ __launch_bounds__(256, 4)
void nodedec_mfma(const float* __restrict__ xw, const float* __restrict__ agg,
                  const int* __restrict__ cnt,
                  const unsigned short* __restrict__ w1n, const unsigned short* __restrict__ w2n,
                  const float* __restrict__ w3pn, const float* __restrict__ nb3,
                  const unsigned short* __restrict__ d1t, const unsigned short* __restrict__ d2t,
                  const unsigned short* __restrict__ d3t,
                  const float* __restrict__ db2, const float* __restrict__ w4pd,
                  const float* __restrict__ db4,
                  float* __restrict__ out) {
    int tid = threadIdx.x;
    int l = tid & 63;
    int g = l >> 4;
    int c = l & 15;
    int gid = blockIdx.x * 256 + tid;
    int i = min(gid, NN - 1);

    float inv = 1.0f / fmaxf((float)cnt[i], 1.0f);
    float x0=xw[i*5+0], x1=xw[i*5+1], x2=xw[i*5+2], x3=xw[i*5+3], x4=xw[i*5+4];
    float e2 = agg[(size_t)i*5+0]*inv, e3 = agg[(size_t)i*5+1]*inv, e4 = agg[(size_t)i*5+2]*inv,
          e5 = agg[(size_t)i*5+3]*inv, e6 = agg[(size_t)i*5+4]*inv;

    unsigned q0 = pk2(x3, x4);
    unsigned q1 = pk2(e2, e3);
    unsigned q2 = pk2(e4, e5);
    unsigned q3 = pk2(e6, 1.0f);

    int srcA = (g & 1) * 32 + c;
    int srcB = srcA + 16;
    bool hi2 = (g & 2) != 0;

    float sN = 0.f;
    NODE_NT(0) NODE_NT(1) NODE_NT(2) NODE_NT(3)

    float dphi = nb3[0] + sN;
    x4 += dphi;
    float u0 = x0 + fmaxf(x0, 0.0f);
    float u1 = x1 + fmaxf(x1, 0.0f);
    float u2 = x2 + fmaxf(x2, 0.0f);
    float u3 = x3 + fmaxf(x3, 0.0f);
    float u4 = x4 + fmaxf(x4, 0.0f);

    unsigned qd0 = pk2(u0, u1);
    unsigned qd1 = pk2(u2, u3);
    unsigned qd2 = pk2(u4, 1.0f);

    float sD = 0.f;
    DEC_NT(0) DEC_NT(1) DEC_NT(2) DEC_NT(3)

    if (gid < NN) out[gid] = db4[0] + sD;
}

// ---------------- scalar node kernels (tier 2) ----------------
__global__ __launch_bounds__(256, 2)
void node_csr(float* __restrict__ xw, const float* __restrict__ eout,
              const int* __restrict__ eidx,
              const int* __restrict__ cnt, const int* __restrict__ start,
              const float* __restrict__ nw1, const float* __restrict__ nb1,
              const float* __restrict__ nw2t, const float* __restrict__ nb2,
              const float* __restrict__ nw3, const float* __restrict__ nb3) {
    int gid = blockIdx.x * blockDim.x + threadIdx.x;
    int i = min(gid, NN - 1);
    bool valid = (gid < NN);

    int nE = cnt[i];
    int base = start[i];
    float g0=0.f, g1=0.f, g2=0.f, g3=0.f, g4=0.f;
    int j = 0;
    for (; j + 1 < nE; j += 2) {
        int e0 = eidx[base + j];
        int e1 = eidx[base + j + 1];
        const float* p0 = eout + (size_t)e0 * 5;
        const float* p1 = eout + (size_t)e1 * 5;
        g0 += p0[0] + p1[0]; g1 += p0[1] + p1[1]; g2 += p0[2] + p1[2];
        g3 += p0[3] + p1[3]; g4 += p0[4] + p1[4];
    }
    if (j < nE) {
        int e0 = eidx[base + j];
        const float* p0 = eout + (size_t)e0 * 5;
        g0 += p0[0]; g1 += p0[1]; g2 += p0[2]; g3 += p0[3]; g4 += p0[4];
    }
    float inv = 1.0f / fmaxf((float)nE, 1.0f);

    float ein_0 = xw[i*5+3];
    float ein_1 = xw[i*5+4];
    float ein_2 = g0 * inv;
    float ein_3 = g1 * inv;
    float ein_4 = g2 * inv;
    float ein_5 = g3 * inv;
    float ein_6 = g4 * inv;

    NODE_MLP_BODY

    if (valid) {
        float x0=xw[i*5+0], x1=xw[i*5+1], x2=xw[i*5+2], x3=xw[i*5+3], x4=xw[i*5+4];
        x4 += dphi;
        xw[i*5+0] = x0 + fmaxf(x0, 0.0f);
        xw[i*5+1] = x1 + fmaxf(x1, 0.0f);
        xw[i*5+2] = x2 + fmaxf(x2, 0.0f);
        xw[i*5+3] = x3 + fmaxf(x3, 0.0f);
        xw[i*5+4] = x4 + fmaxf(x4, 0.0f);
    }
}

__global__ __launch_bounds__(256, 2)
void node_dec(const float* __restrict__ xw, const float* __restrict__ eout,
              const int* __restrict__ eidx,
              const int* __restrict__ cnt, const int* __restrict__ start,
              const float* __restrict__ nw1, const float* __restrict__ nb1,
              const float* __restrict__ nw2t, const float* __restrict__ nb2,
              const float* __restrict__ nw3, const float* __restrict__ nb3,
              const float* __restrict__ dw1, const float* __restrict__ db1,
              const float* __restrict__ dw2t, const float* __restrict__ db2,
              const float* __restrict__ dw3t, const float* __restrict__ db3,
              const float* __restrict__ dw4, const float* __restrict__ db4,
              float* __restrict__ out) {
    int gid = blockIdx.x * blockDim.x + threadIdx.x;
    int i = min(gid, NN - 1);
    bool valid = (gid < NN);

    int nE = cnt[i];
    int base = start[i];
    float g0=0.f, g1=0.f, g2=0.f, g3=0.f, g4=0.f;
    int j = 0;
    for (; j + 1 < nE; j += 2) {
        int e0 = eidx[base + j];
        int e1 = eidx[base + j + 1];
        const float* p0 = eout + (size_t)e0 * 5;
        const float* p1 = eout + (size_t)e1 * 5;
        g0 += p0[0] + p1[0]; g1 += p0[1] + p1[1]; g2 += p0[2] + p1[2];
        g3 += p0[3] + p1[3]; g4 += p0[4] + p1[4];
    }
    if (j < nE) {
        int e0 = eidx[base + j];
        const float* p0 = eout + (size_t)e0 * 5;
        g0 += p0[0]; g1 += p0[1]; g2 += p0[2]; g3 += p0[3]; g4 += p0[4];
    }
    float inv = 1.0f / fmaxf((float)nE, 1.0f);

    float x0=xw[i*5+0], x1=xw[i*5+1], x2=xw[i*5+2], x3=xw[i*5+3], x4=xw[i*5+4];

    float dphi_out;
    {
        float ein_0 = x3;
        float ein_1 = x4;
        float ein_2 = g0 * inv;
        float ein_3 = g1 * inv;
        float ein_4 = g2 * inv;
        float ein_5 = g3 * inv;
        float ein_6 = g4 * inv;
        NODE_MLP_BODY
        dphi_out = dphi;
    }

    x4 += dphi_out;
    float u0 = x0 + fmaxf(x0, 0.0f);
    float u1 = x1 + fmaxf(x1, 0.0f);
    float u2 = x2 + fmaxf(x2, 0.0f);
    float u3 = x3 + fmaxf(x3, 0.0f);
    float u4 = x4 + fmaxf(x4, 0.0f);

    {
        float ein_0 = u0, ein_1 = u1, ein_2 = u2, ein_3 = u3, ein_4 = u4;
        DECODER_BODY
        if (valid) out[gid] = o;
    }
}

// ---------------- fallback (atomic) kernels ----------------
__global__ void init_fb(const float* __restrict__ x, float* __restrict__ xw,
                        float* __restrict__ counts, float* __restrict__ agg) {
    int i = blockIdx.x * blockDim.x + threadIdx.x;
    if (i < NN) {
#pragma unroll
        for (int j = 0; j < 5; j++) { xw[i*5+j] = x[i*5+j]; agg[i*5+j] = 0.0f; }
        counts[i] = 0.0f;
    }
}

__global__ void count_f(const int* __restrict__ dst, float* __restrict__ counts) {
    int e = blockIdx.x * blockDim.x + threadIdx.x;
    atomicAdd(&counts[dst[e]], 1.0f);
}

__global__ __launch_bounds__(256, 2)
void edge_atomic(const float* __restrict__ xw, const float* __restrict__ edge_attr,
                 const int* __restrict__ src_idx, const int* __restrict__ dst_idx,
                 const float* __restrict__ ew1, const float* __restrict__ eb1,
                 const float* __restrict__ ew2t, const float* __restrict__ eb2,
                 const float* __restrict__ ew3, const float* __restrict__ eb3,
                 float* __restrict__ agg) {
    int e = blockIdx.x * blockDim.x + threadIdx.x;
    int s = src_idx[e];
    int d = dst_idx[e];

    float xs_0=xw[s*5+0], xs_1=xw[s*5+1], xs_2=xw[s*5+2], xs_4=xw[s*5+4];
    float xd_0=xw[d*5+0], xd_1=xw[d*5+1], xd_2=xw[d*5+2], xd_4=xw[d*5+4];
    float ea_0=edge_attr[(size_t)e*5+0], ea_1=edge_attr[(size_t)e*5+1],
          ea_2=edge_attr[(size_t)e*5+2], ea_3=edge_attr[(size_t)e*5+3],
          ea_4=edge_attr[(size_t)e*5+4];

    float ein_0 = xd_0 - xs_0;
    float ein_1 = xd_1 - xs_1;
    float ein_2 = xd_2 - xs_2;
    float ein_3 = sqrtf(ein_0*ein_0 + ein_1*ein_1 + ein_2*ein_2);
    float ein_4 = ea_0, ein_5 = ea_1, ein_6 = ea_2, ein_7 = ea_3, ein_8 = ea_4;
    float ein_9 = xs_4, ein_10 = xd_4;

    EDGE_MLP_BODY

    atomicAdd(&agg[d*5+0], ea_0 + o_0);
    atomicAdd(&agg[d*5+1], ea_1 + o_1);
    atomicAdd(&agg[d*5+2], ea_2 + o_2);
    atomicAdd(&agg[d*5+3], ea_3 + o_3);
    atomicAdd(&agg[d*5+4], ea_4 + o_4);
}

__global__ __launch_bounds__(256, 2)
void node_agg(float* __restrict__ xw, float* __restrict__ agg,
              const float* __restrict__ counts,
              const float* __restrict__ nw1, const float* __restrict__ nb1,
              const float* __restrict__ nw2t, const float* __restrict__ nb2,
              const float* __restrict__ nw3, const float* __restrict__ nb3) {
    int gid = blockIdx.x * blockDim.x + threadIdx.x;
    int i = min(gid, NN - 1);
    bool valid = (gid < NN);

    float inv = 1.0f / fmaxf(counts[i], 1.0f);
    float ein_0 = xw[i*5+3];
    float ein_1 = xw[i*5+4];
    float ein_2 = agg[i*5+0] * inv;
    float ein_3 = agg[i*5+1] * inv;
    float ein_4 = agg[i*5+2] * inv;
    float ein_5 = agg[i*5+3] * inv;
    float ein_6 = agg[i*5+4] * inv;

    NODE_MLP_BODY

    if (valid) {
        float x0=xw[i*5+0], x1=xw[i*5+1], x2=xw[i*5+2], x3=xw[i*5+3], x4=xw[i*5+4];
        x4 += dphi;
        xw[i*5+0] = x0 + fmaxf(x0, 0.0f);
        xw[i*5+1] = x1 + fmaxf(x1, 0.0f);
        xw[i*5+2] = x2 + fmaxf(x2, 0.0f);
        xw[i*5+3] = x3 + fmaxf(x3, 0.0f);
        xw[i*5+4] = x4 + fmaxf(x4, 0.0f);
        agg[i*5+0]=0.f; agg[i*5+1]=0.f; agg[i*5+2]=0.f; agg[i*5+3]=0.f; agg[i*5+4]=0.f;
    }
}

__global__ __launch_bounds__(256, 2)
void decoder_kernel(const float* __restrict__ xw,
                    const float* __restrict__ dw1, const float* __restrict__ db1,
                    const float* __restrict__ dw2t, const float* __restrict__ db2,
                    const float* __restrict__ dw3t, const float* __restrict__ db3,
                    const float* __restrict__ dw4, const float* __restrict__ db4,
                    float* __restrict__ out) {
    int gid = blockIdx.x * blockDim.x + threadIdx.x;
    int i = min(gid, NN - 1);
    bool valid = (gid < NN);

    float ein_0 = xw[i*5+0], ein_1 = xw[i*5+1], ein_2 = xw[i*5+2],
          ein_3 = xw[i*5+3], ein_4 = xw[i*5+4];

    DECODER_BODY

    if (valid) out[gid] = o;
}

extern "C" void kernel_launch(void* const* d_in, const int* in_sizes, int n_in,
                              void* d_out, int out_size, void* d_ws, size_t ws_size,
                              hipStream_t stream) {
    const float* x         = (const float*)d_in[0];
    const float* edge_attr = (const float*)d_in[1];
    const float* ew1 = (const float*)d_in[2];
    const float* eb1 = (const float*)d_in[3];
    const float* ew2 = (const float*)d_in[4];
    const float* eb2 = (const float*)d_in[5];
    const float* ew3 = (const float*)d_in[6];
    const float* eb3 = (const float*)d_in[7];
    const float* nw1 = (const float*)d_in[8];
    const float* nb1 = (const float*)d_in[9];
    const float* nw2 = (const float*)d_in[10];
    const float* nb2 = (const float*)d_in[11];
    const float* nw3 = (const float*)d_in[12];
    const float* nb3 = (const float*)d_in[13];
    const float* dw1 = (const float*)d_in[14];
    const float* db1 = (const float*)d_in[15];
    const float* dw2 = (const float*)d_in[16];
    const float* db2 = (const float*)d_in[17];
    const float* dw3 = (const float*)d_in[18];
    const float* db3 = (const float*)d_in[19];
    const float* dw4 = (const float*)d_in[20];
    const float* db4 = (const float*)d_in[21];
    const int* edge_index = (const int*)d_in[22];
    const int* src = edge_index;
    const int* dst = edge_index + NE;
    float* out = (float*)d_out;

    const size_t WS1 = (size_t)10420992 * 4;             // base layout
    const size_t WS2 = (size_t)(10420992 + 500000) * 4;  // + agg[NN*5]

    if (ws_size >= WS1) {
        float* xw      = (float*)d_ws;
        int*   cnt     = (int*)d_ws + 500000;
        int*   start   = (int*)d_ws + 600000;
        int*   bcur    = (int*)d_ws + 700000;
        // node/decoder MFMA weights live in bcur slack (701024..709472)
        unsigned short* w1n = (unsigned short*)((int*)d_ws + 701024);
        unsigned short* w2n = (unsigned short*)((int*)d_ws + 702048);
        float* w3pn  = (float*)d_ws + 704096;
        unsigned short* d1t = (unsigned short*)((int*)d_ws + 704224);
        unsigned short* d2t = (unsigned short*)((int*)d_ws + 705248);
        unsigned short* d3t = (unsigned short*)((int*)d_ws + 707296);
        float* w4pd  = (float*)d_ws + 709344;
        int*   bsum    = (int*)d_ws + 800000;
        int*   boff    = (int*)d_ws + 800512;
        float* nw2t    = (float*)d_ws + 805120;
        float* dw2t    = (float*)d_ws + 809216;
        float* dw3t    = (float*)d_ws + 813312;
        int*   eidx    = (int*)d_ws + 817408;
        float* eout    = (float*)d_ws + 2417408;
        int*   ebkt    = (int*)d_ws + 2417408;   // alias: dead before edge_mfma
        unsigned short* w1tb = (unsigned short*)((int*)d_ws + 10417408);
        unsigned short* w2tb = (unsigned short*)((int*)d_ws + 10418432);
        float* w3p8    = (float*)d_ws + 10420480;
        float* agg     = (float*)d_ws + 10420992;  // tier-1 only

        transpose64<<<64, 64, 0, stream>>>(nw2, nw2t);
        transpose64<<<64, 64, 0, stream>>>(dw2, dw2t);
        transpose64<<<64, 64, 0, stream>>>(dw3, dw3t);
        prep_wb<<<1, 256, 0, stream>>>(ew1, eb1, ew2, ew3, eb2, w1tb, w2tb, w3p8);
        prep_nd<<<1, 256, 0, stream>>>(nw1, nb1, nw2, nw3, nb2,
                                       dw1, db1, dw2, dw3, dw4, db3,
                                       w1n, w2n, w3pn, d1t, d2t, d3t, w4pd);

        init_xw<<<NGB, 256, 0, stream>>>(x, xw, bsum, bcur);
        bhist_kernel<<<250, 256, 0, stream>>>(dst, bsum);
        scanb_kernel<<<1, 512, 0, stream>>>(bsum, boff);
        sort_pass1<<<250, 256, 0, stream>>>(dst, boff, bcur, ebkt);
        sort_pass2<<<NBKT, 256, 0, stream>>>(ebkt, dst, boff, bsum, eidx, cnt, start);

        if (ws_size >= WS2) {
            // tier 1: gather + MFMA node/decoder kernels
            edge_mfma<<<NE/256, 256, 0, stream>>>(xw, edge_attr, src, dst,
                                                  w1tb, w2tb, w3p8, eb3, eout);
            gather4<<<(NN*4 + 255)/256, 256, 0, stream>>>(eout, eidx, cnt, start, agg);
            node_mfma<<<NGB, 256, 0, stream>>>(xw, agg, cnt, w1n, w2n, w3pn, nb3);
            edge_mfma<<<NE/256, 256, 0, stream>>>(xw, edge_attr, src, dst,
                                                  w1tb, w2tb, w3p8, eb3, eout);
            gather4<<<(NN*4 + 255)/256, 256, 0, stream>>>(eout, eidx, cnt, start, agg);
            nodedec_mfma<<<NGB, 256, 0, stream>>>(xw, agg, cnt, w1n, w2n, w3pn, nb3,
                                                  d1t, d2t, d3t, db2, w4pd, db4, out);
        } else {
            // tier 2: round-15 proven path
            edge_mfma<<<NE/256, 256, 0, stream>>>(xw, edge_attr, src, dst,
                                                  w1tb, w2tb, w3p8, eb3, eout);
            node_csr<<<NGB, 256, 0, stream>>>(xw, eout, eidx, cnt, start,
                                              nw1, nb1, nw2t, nb2, nw3, nb3);
            edge_mfma<<<NE/256, 256, 0, stream>>>(xw, edge_attr, src, dst,
                                                  w1tb, w2tb, w3p8, eb3, eout);
            node_dec<<<NGB, 256, 0, stream>>>(xw, eout, eidx, cnt, start,
                                              nw1, nb1, nw2t, nb2, nw3, nb3,
                                              dw1, db1, dw2t, db2, dw3t, db3, dw4, db4,
                                              out);
        }
    } else {
        float* xw     = (float*)d_ws;
        float* counts = (float*)d_ws + 500000;
        float* agg    = (float*)d_ws + 600000;
        float* ew2t   = (float*)d_ws + 1100000;
        float* nw2t   = (float*)d_ws + 1104096;
        float* dw2t   = (float*)d_ws + 1108192;
        float* dw3t   = (float*)d_ws + 1112288;

        transpose64<<<64, 64, 0, stream>>>(ew2, ew2t);
        transpose64<<<64, 64, 0, stream>>>(nw2, nw2t);
        transpose64<<<64, 64, 0, stream>>>(dw2, dw2t);
        transpose64<<<64, 64, 0, stream>>>(dw3, dw3t);

        init_fb<<<NGB, 256, 0, stream>>>(x, xw, counts, agg);
        count_f<<<NE/256, 256, 0, stream>>>(dst, counts);

        for (int it = 0; it < 2; it++) {
            edge_atomic<<<NE/256, 256, 0, stream>>>(xw, edge_attr, src, dst,
                                                    ew1, eb1, ew2t, eb2, ew3, eb3, agg);
            node_agg<<<NGB, 256, 0, stream>>>(xw, agg, counts,
                                              nw1, nb1, nw2t, nb2, nw3, nb3);
        }
        decoder_kernel<<<NGB, 256, 0, stream>>>(xw, dw1, db1, dw2t, db2,
                                                dw3t, db3, dw4, db4, out);
    }
}